// Round 10
// baseline (147.380 us; speedup 1.0000x reference)
//
#include <hip/hip_runtime.h>

// ---------------------------------------------------------------------------
// CrossModeAttention: B=4, N=1024, D1=D2=512, C=512, H=8, DH=64, LAYERS=3
// Q,K layer-invariant => P = exp(QK^T*scale) computed ONCE. R10: P and Vt
// stored FP8 e4m3 (in-block swizzled) -> half traffic, fp8 MFMA in k_pv.
// ---------------------------------------------------------------------------

#define LOG2E 1.44269504088896f

using f32x4   = __attribute__((ext_vector_type(4))) float;
using short8  = __attribute__((ext_vector_type(8))) short;
using ushort8 = __attribute__((ext_vector_type(8))) unsigned short;
using uchar8  = __attribute__((ext_vector_type(8))) unsigned char;
using uchar16 = __attribute__((ext_vector_type(16))) unsigned char;

__device__ inline unsigned short f2bf(float f) {
  unsigned u = __builtin_bit_cast(unsigned, f);
  u += 0x7fffu + ((u >> 16) & 1u);   // RNE
  return (unsigned short)(u >> 16);
}
__device__ inline float bf2f(unsigned short h) {
  unsigned u = (unsigned)h << 16;
  return __builtin_bit_cast(float, u);
}

// f32 -> OCP e4m3fn, RNE, subnormal-correct for |f| < 2^-6, clamp at 448.
__device__ inline unsigned char f2e4m3(float f) {
  unsigned u = __builtin_bit_cast(unsigned, f);
  unsigned sign = (u >> 24) & 0x80u;
  unsigned a = u & 0x7fffffffu;
  if (a < 0x3c800000u) {                       // |f| < 2^-6: subnormal (or 0)
    float af = __builtin_bit_cast(float, a);
    int q = (int)rintf(af * 512.0f);           // units of 2^-9; q==8 -> 0x08
    return (unsigned char)(sign | q);
  }
  unsigned v = a + (0x7ffffu + ((a >> 20) & 1u));   // RNE to 3 mantissa bits
  int E = (int)(v >> 23) - 120;                     // e + 7
  unsigned M = (v >> 20) & 7u;
  if (E >= 16) return (unsigned char)(sign | 0x7eu);
  return (unsigned char)(sign | (E << 3) | M);
}

__device__ inline f32x4 mfma_bf16(short8 a, short8 b, f32x4 c) {
  return __builtin_amdgcn_mfma_f32_16x16x32_bf16(a, b, c, 0, 0, 0);
}

__device__ inline void gload_lds16(const void* g, void* l) {
  __builtin_amdgcn_global_load_lds(
      (const __attribute__((address_space(1))) unsigned int*)g,
      (__attribute__((address_space(3))) unsigned int*)l, 16, 0, 0);
}

// XOR swizzle for 128B-row LDS tiles (G4)
__device__ inline int swz(int row, int byte_in_row) {
  return row * 128 + (byte_in_row ^ ((row & 7) << 4));
}

// ---------------------------------------------------------------------------
// Merged convert: xb bf16 [4096][1024] from x1|x2, then Wq,Wk,Wv -> bf16.
// ---------------------------------------------------------------------------
__global__ __launch_bounds__(256) void k_convert_all(
    const float* __restrict__ x1, const float* __restrict__ x2,
    const float* __restrict__ Wq, const float* __restrict__ Wk,
    const float* __restrict__ Wv,
    unsigned short* __restrict__ xb, unsigned short* __restrict__ Wqb,
    unsigned short* __restrict__ Wkb, unsigned short* __restrict__ Wvb) {
  int i = blockIdx.x * 256 + threadIdx.x;
  const float* src;
  unsigned short* dst;
  if (i < 524288) {
    int e0 = i * 8, m = e0 >> 10, d = e0 & 1023;
    src = (d < 512) ? (x1 + (size_t)m * 512 + d)
                    : (x2 + (size_t)m * 512 + (d - 512));
    dst = xb + (size_t)e0;
  } else if (i < 557056) {
    int j = (i - 524288) * 8;
    src = Wq + j; dst = Wqb + j;
  } else if (i < 589824) {
    int j = (i - 557056) * 8;
    src = Wk + j; dst = Wkb + j;
  } else {
    int j = (i - 589824) * 8;
    src = Wv + j; dst = Wvb + j;
  }
  float4 a = ((const float4*)src)[0];
  float4 b = ((const float4*)src)[1];
  ushort8 o;
  o[0] = f2bf(a.x); o[1] = f2bf(a.y); o[2] = f2bf(a.z); o[3] = f2bf(a.w);
  o[4] = f2bf(b.x); o[5] = f2bf(b.y); o[6] = f2bf(b.z); o[7] = f2bf(b.w);
  *(ushort8*)dst = o;
}

// ---------------------------------------------------------------------------
// Projections: 128x128 tile, BK=64, global_load_lds. z=0 Q, z=1 K, z=2 V.
// ---------------------------------------------------------------------------
__global__ __launch_bounds__(256) void k_proj(
    const unsigned short* __restrict__ xb,
    const unsigned short* __restrict__ Wqb,
    const unsigned short* __restrict__ Wkb,
    const unsigned short* __restrict__ Wvb,
    unsigned short* __restrict__ Qb, unsigned short* __restrict__ Kb,
    float* __restrict__ Vf) {
  __shared__ __align__(16) unsigned short Atile[128 * 64];
  __shared__ __align__(16) unsigned short Btile[128 * 64];

  const int id  = blockIdx.x;
  const int z   = id % 3;
  const int rem = id / 3;
  const int c0  = (rem & 3) * 128;
  const int m0  = (rem >> 2) * 128;

  const int K    = (z == 2) ? 1024 : 512;
  const int aoff = (z == 1) ? 512 : 0;
  const unsigned short* W = (z == 0) ? Wqb : (z == 1) ? Wkb : Wvb;

  const int t  = threadIdx.x;
  const int w  = t >> 6, l = t & 63;
  const int lr = l & 15, ls = l >> 4;
  const int wr = w >> 1, wc = w & 1;

  const int srow  = l >> 3;
  const int scol8 = (l & 7) * 8;

  f32x4 acc[4][4] = {};

  for (int k0 = 0; k0 < K; k0 += 64) {
#pragma unroll
    for (int j = 0; j < 4; ++j) {
      int ch  = w * 4 + j;
      int row = ch * 8 + srow;
      gload_lds16(xb + (size_t)(m0 + row) * 1024 + aoff + k0 + scol8,
                  Atile + ch * 512);
      gload_lds16(W + (size_t)(c0 + row) * K + k0 + scol8,
                  Btile + ch * 512);
    }
    __syncthreads();
#pragma unroll
    for (int ks = 0; ks < 2; ++ks) {
      short8 af[4], bf[4];
#pragma unroll
      for (int mf = 0; mf < 4; ++mf)
        af[mf] = *(const short8*)(Atile + (wr * 64 + mf * 16 + lr) * 64 +
                                  ks * 32 + ls * 8);
#pragma unroll
      for (int nf = 0; nf < 4; ++nf)
        bf[nf] = *(const short8*)(Btile + (wc * 64 + nf * 16 + lr) * 64 +
                                  ks * 32 + ls * 8);
#pragma unroll
      for (int mf = 0; mf < 4; ++mf)
#pragma unroll
        for (int nf = 0; nf < 4; ++nf)
          acc[mf][nf] = mfma_bf16(af[mf], bf[nf], acc[mf][nf]);
    }
    __syncthreads();
  }

#pragma unroll
  for (int mf = 0; mf < 4; ++mf)
#pragma unroll
    for (int nf = 0; nf < 4; ++nf)
#pragma unroll
      for (int r = 0; r < 4; ++r) {
        int m = m0 + wr * 64 + mf * 16 + ls * 4 + r;
        int c = c0 + wc * 64 + nf * 16 + lr;
        float v = acc[mf][nf][r];
        if (z == 2) {
          Vf[(size_t)m * 512 + c] = v;
        } else {
          int b = m >> 10, n = m & 1023, h = c >> 6, dh = c & 63;
          size_t idx = ((size_t)(b * 8 + h) * 1024 + n) * 64 + dh;
          (z == 0 ? Qb : Kb)[idx] = f2bf(v);
        }
      }
}

// ---------------------------------------------------------------------------
// Transpose (initial): Vf f32 [B,N,512] -> Vt [B,H,64,N], swizzled in-block.
// mode 0: bf16 (2048B rows, fallback). mode 1: fp8 (1024B rows).
// ---------------------------------------------------------------------------
__global__ __launch_bounds__(256) void k_transpose_v(
    const float* __restrict__ Vf, void* __restrict__ Vt, int mode) {
  __shared__ unsigned short tile[64 * 66];
  const int bh = blockIdx.y;
  const int b = bh >> 3, h = bh & 7;
  const int n0 = blockIdx.x * 64;
  const int t = threadIdx.x;
  {
    int n = t >> 2, dh0 = (t & 3) * 16;
    const float* src = Vf + ((size_t)b * 1024 + n0 + n) * 512 + h * 64 + dh0;
    unsigned short* dst = tile + n * 66 + dh0;
#pragma unroll
    for (int j = 0; j < 16; j += 4) {
      float4 v = *(const float4*)(src + j);
      dst[j + 0] = f2bf(v.x); dst[j + 1] = f2bf(v.y);
      dst[j + 2] = f2bf(v.z); dst[j + 3] = f2bf(v.w);
    }
  }
  __syncthreads();
#pragma unroll
  for (int it = 0; it < 2; ++it) {
    int dh = (t >> 3) + it * 32, n8 = (t & 7) * 8;
    if (mode == 0) {
      ushort8 o;
#pragma unroll
      for (int j = 0; j < 8; ++j) o[j] = tile[(n8 + j) * 66 + dh];
      char* dst = (char*)Vt + ((size_t)(bh * 64 + dh)) * 2048 + n0 * 2 +
                  ((n8 * 2) ^ ((dh & 7) << 4));
      *(ushort8*)dst = o;
    } else {
      uchar8 o;
#pragma unroll
      for (int j = 0; j < 8; ++j) o[j] = f2e4m3(bf2f(tile[(n8 + j) * 66 + dh]));
      int byte = n0 + n8;
      char* dst = (char*)Vt + ((size_t)(bh * 64 + dh)) * 1024 + (byte & ~127) +
                  ((byte & 127) ^ ((dh & 7) << 4));
      *(uchar8*)dst = o;
    }
  }
}

// ---------------------------------------------------------------------------
// k_scores: P = exp(QK^T*scale) -> FP8 e4m3, masked (s==0 -> 0). Grid 1024
// XCD-chunked: head = lid>>5, qtile = (lid>>1)&15, khalf = lid&1.
// P fp8 [32][1024][1024B], swizzled within each 128B block (byte ^ (n&7)<<4).
// Partial row sums (f32, pre-rounding) -> lsm[khalf][32][1024].
// ---------------------------------------------------------------------------
__global__ __launch_bounds__(256) void k_scores(
    const unsigned short* __restrict__ Qb,
    const unsigned short* __restrict__ Kb,
    unsigned char* __restrict__ Pmat, float* __restrict__ lsum_g) {
  __shared__ char lds[8192 + 4 * 16 * 80];
  char* kbuf = lds;
  const int id  = blockIdx.x;
  const int lid = (id & 7) * 128 + (id >> 3);
  const int bh  = lid >> 5;
  const int q0  = ((lid >> 1) & 15) * 64;
  const int kh  = lid & 1;
  const int t = threadIdx.x;
  const int w = t >> 6, l = t & 63, lr = l & 15, ls = l >> 4;
  char* pbuf = lds + 8192 + w * (16 * 80);

  const float sclog2e = 0.0637587160f;   // (512^-0.5) * log2(e)

  short8 qa[2];
  {
    const unsigned short* Qg =
        Qb + ((size_t)bh * 1024 + q0 + w * 16 + lr) * 64 + ls * 8;
    qa[0] = *(const short8*)(Qg);
    qa[1] = *(const short8*)(Qg + 32);
  }

  const unsigned short* Kg = Kb + (size_t)bh * 1024 * 64 + kh * 512 * 64;
  unsigned char* Pg = Pmat + (size_t)bh * 1024 * 1024;

  float lacc[4] = {0.f, 0.f, 0.f, 0.f};

  const int srow = t >> 3, sc8 = (t & 7) * 8;
  int4 kreg[2];
  kreg[0] = *(const int4*)(Kg + (size_t)(srow)*64 + sc8);
  kreg[1] = *(const int4*)(Kg + (size_t)(srow + 32) * 64 + sc8);

  for (int kc = 0; kc < 8; ++kc) {
    *(int4*)(kbuf + swz(srow, sc8 * 2)) = kreg[0];
    *(int4*)(kbuf + swz(srow + 32, sc8 * 2)) = kreg[1];
    __syncthreads();
    if (kc < 7) {
      kreg[0] = *(const int4*)(Kg + (size_t)((kc + 1) * 64 + srow) * 64 + sc8);
      kreg[1] = *(const int4*)(Kg + (size_t)((kc + 1) * 64 + srow + 32) * 64 + sc8);
    }

    f32x4 s[4] = {};
#pragma unroll
    for (int kk = 0; kk < 2; ++kk) {
#pragma unroll
      for (int nt = 0; nt < 4; ++nt) {
        short8 bk = *(const short8*)(kbuf + swz(nt * 16 + lr, kk * 64 + ls * 16));
        s[nt] = mfma_bf16(qa[kk], bk, s[nt]);
      }
    }

#pragma unroll
    for (int nt = 0; nt < 4; ++nt)
#pragma unroll
      for (int r = 0; r < 4; ++r) {
        float sv = s[nt][r];
        float pv = (sv == 0.f) ? 0.f : exp2f(sv * sclog2e);
        lacc[r] += pv;
        pbuf[(ls * 4 + r) * 80 + nt * 16 + lr] = (char)f2e4m3(pv);
      }

    // write-out: wave tile = 16 rows x 64B; lane -> (prow = l>>2, pchk = l&3)
    int gkc = kh * 8 + kc;
    {
      int prow = l >> 2, pchk = l & 3;
      uchar16 pv16 = *(const uchar16*)(pbuf + prow * 80 + pchk * 16);
      int n = q0 + w * 16 + prow;
      *(uchar16*)(Pg + (size_t)n * 1024 + (gkc >> 1) * 128 +
                  (((gkc & 1) * 64 + pchk * 16) ^ ((n & 7) << 4))) = pv16;
    }
    __syncthreads();
  }

#pragma unroll
  for (int r = 0; r < 4; ++r) {
#pragma unroll
    for (int off = 1; off < 16; off <<= 1)
      lacc[r] += __shfl_xor(lacc[r], off, 64);
  }
  if (lr == 0) {
#pragma unroll
    for (int r = 0; r < 4; ++r)
      lsum_g[kh * 32768 + (size_t)bh * 1024 + q0 + w * 16 + ls * 4 + r] =
          lacc[r];
  }
}

// ---------------------------------------------------------------------------
// k_pv: fp8 x fp8 MFMA. V1h[n, h*64+dh] = (1/l[n]) * sum_{m half} P[n,m]*V[dh,m].
// BK=128 fp8 elements (128B rows), 4 iterations, gload_lds 2-phase dbuf.
// Grid 1024 XCD-chunked: head = lid>>5, ntile = (lid>>1)&15, mhalf = lid&1.
// ---------------------------------------------------------------------------
__global__ __launch_bounds__(256) void k_pv(
    const unsigned char* __restrict__ Pmat,
    const unsigned char* __restrict__ Vt,
    const float* __restrict__ lsum_g, float* __restrict__ V1a,
    float* __restrict__ V1b) {
  __shared__ __align__(16) char Ab[2][8192];
  __shared__ __align__(16) char Bb[2][8192];
  const int id  = blockIdx.x;
  const int lid = (id & 7) * 128 + (id >> 3);
  const int head = lid >> 5;
  const int n0   = ((lid >> 1) & 15) * 64;
  const int mh   = lid & 1;
  const int t = threadIdx.x;
  const int w = t >> 6, l = t & 63, lr = l & 15, ls = l >> 4;

  const char* Pg = (const char*)(Pmat + (size_t)head * 1024 * 1024) +
                   (size_t)n0 * 1024 + mh * 512;
  const char* Vg = (const char*)(Vt + (size_t)head * 64 * 1024) + mh * 512;

  const int srow = w * 16 + (l >> 3);
  const int sc16 = (l & 7) * 16;

  f32x4 acc[4] = {};

  auto STAGE = [&](int buf, int kc) {
#pragma unroll
    for (int j = 0; j < 2; ++j) {
      int row = srow + j * 8;
      gload_lds16(Pg + (size_t)row * 1024 + kc * 128 + sc16,
                  &Ab[buf][w * 2048 + j * 1024]);
      gload_lds16(Vg + (size_t)row * 1024 + kc * 128 + sc16,
                  &Bb[buf][w * 2048 + j * 1024]);
    }
  };

  STAGE(0, 0);
  __syncthreads();
  int cur = 0;
  for (int kc = 0; kc < 4; ++kc) {
    if (kc < 3) STAGE(cur ^ 1, kc + 1);
#pragma unroll
    for (int ks = 0; ks < 4; ++ks) {
      long af = *(const long*)(&Ab[cur][swz(w * 16 + lr, ks * 32 + ls * 8)]);
#pragma unroll
      for (int nf = 0; nf < 4; ++nf) {
        long bf8 = *(const long*)(&Bb[cur][swz(nf * 16 + lr, ks * 32 + ls * 8)]);
        acc[nf] = __builtin_amdgcn_mfma_f32_16x16x32_fp8_fp8(af, bf8, acc[nf],
                                                             0, 0, 0);
      }
    }
    __syncthreads();
    cur ^= 1;
  }

  float* V1 = mh ? V1b : V1a;
  const int b = head >> 3, h = head & 7;
#pragma unroll
  for (int r = 0; r < 4; ++r) {
    int n = n0 + w * 16 + ls * 4 + r;
    float lv = lsum_g[(size_t)head * 1024 + n] +
               lsum_g[32768 + (size_t)head * 1024 + n];
    float rinv = (lv > 0.f) ? 1.f / lv : 0.f;
#pragma unroll
    for (int nf = 0; nf < 4; ++nf)
      V1[((size_t)b * 1024 + n) * 512 + h * 64 + nf * 16 + lr] =
          acc[nf][r] * rinv;
  }
}

// ---------------------------------------------------------------------------
// Fused LayerNorm (+ optional transpose): y = LN(V1a+V1b+Vf).
// mode 0: bf16 Vt (fallback). mode 1: fp8 Vt. mode 2: no Vt (final layer).
// Grid 256 (16 rows per block).
// ---------------------------------------------------------------------------
__global__ __launch_bounds__(256) void k_ln_t(
    const float* __restrict__ V1a, const float* __restrict__ V1b,
    const float* __restrict__ Vf_in,
    const float* __restrict__ gamma, const float* __restrict__ beta,
    float* __restrict__ Vf_out, void* __restrict__ Vt, int mode) {
  __shared__ unsigned short tile[16 * 520];
  const int blk = blockIdx.x;
  const int b  = blk >> 6;
  const int n0 = (blk & 63) * 16;
  const int t = threadIdx.x;
  const int row = t >> 4;
  const int c0  = (t & 15) * 32;
  const size_t base = ((size_t)b * 1024 + n0 + row) * 512 + c0;

  float x[32];
  float s = 0.f, sq = 0.f;
#pragma unroll
  for (int j = 0; j < 32; j += 4) {
    float4 a0 = *(const float4*)(V1a + base + j);
    float4 a1 = *(const float4*)(V1b + base + j);
    float4 v = *(const float4*)(Vf_in + base + j);
    float4 y = {a0.x + a1.x + v.x, a0.y + a1.y + v.y, a0.z + a1.z + v.z,
                a0.w + a1.w + v.w};
    x[j + 0] = y.x; x[j + 1] = y.y; x[j + 2] = y.z; x[j + 3] = y.w;
    s  += y.x + y.y + y.z + y.w;
    sq += y.x * y.x + y.y * y.y + y.z * y.z + y.w * y.w;
  }
#pragma unroll
  for (int off = 1; off < 16; off <<= 1) {
    s  += __shfl_xor(s, off, 64);
    sq += __shfl_xor(sq, off, 64);
  }
  float mu   = s * (1.f / 512.f);
  float var  = sq * (1.f / 512.f) - mu * mu;
  float rstd = rsqrtf(var + 1e-5f);

  unsigned short* trow = tile + row * 520 + c0;
#pragma unroll
  for (int j = 0; j < 32; j += 4) {
    float4 g = *(const float4*)(gamma + c0 + j);
    float4 bb = *(const float4*)(beta + c0 + j);
    float4 y;
    y.x = (x[j + 0] - mu) * rstd * g.x + bb.x;
    y.y = (x[j + 1] - mu) * rstd * g.y + bb.y;
    y.z = (x[j + 2] - mu) * rstd * g.z + bb.z;
    y.w = (x[j + 3] - mu) * rstd * g.w + bb.w;
    *(float4*)(Vf_out + base + j) = y;
    if (mode != 2) {
      trow[j + 0] = f2bf(y.x); trow[j + 1] = f2bf(y.y);
      trow[j + 2] = f2bf(y.z); trow[j + 3] = f2bf(y.w);
    }
  }
  if (mode == 2) return;
  __syncthreads();

#pragma unroll
  for (int it = 0; it < 2; ++it) {
    int d = t + it * 256;
    int h = d >> 6, dh = d & 63;
    int sw = (dh & 7) << 4;
    if (mode == 0) {
      ushort8 o0, o1;
#pragma unroll
      for (int j = 0; j < 8; ++j) {
        o0[j] = tile[j * 520 + d];
        o1[j] = tile[(j + 8) * 520 + d];
      }
      int byte0 = n0 * 2;
      char* rowb = (char*)Vt + ((size_t)((b * 8 + h) * 64 + dh)) * 2048 +
                   (byte0 & ~127);
      *(ushort8*)(rowb + ((byte0 & 127) ^ sw)) = o0;
      *(ushort8*)(rowb + (((byte0 & 127) + 16) ^ sw)) = o1;
    } else {
      uchar16 o;
#pragma unroll
      for (int j = 0; j < 16; ++j) o[j] = f2e4m3(bf2f(tile[j * 520 + d]));
      char* rowb = (char*)Vt + ((size_t)((b * 8 + h) * 64 + dh)) * 1024 +
                   (n0 & ~127);
      *(uchar16*)(rowb + ((n0 & 127) ^ sw)) = o;
    }
  }
}

// ---------------------------------------------------------------------------
// Fallback fused flash attention (ws too small only; bf16 Vt mode 0)
// ---------------------------------------------------------------------------
__global__ __launch_bounds__(256) void k_attn(
    const unsigned short* __restrict__ Qb,
    const unsigned short* __restrict__ Kb,
    const unsigned short* __restrict__ Vt,
    float* __restrict__ V1) {
  __shared__ char lds[8192 + 8192 + 4 * 16 * 144];
  char* kbuf = lds;
  char* vbuf = lds + 8192;
  const int bh = blockIdx.y;
  const int q0 = blockIdx.x * 64;
  const int t = threadIdx.x;
  const int w = t >> 6, l = t & 63, lr = l & 15, ls = l >> 4;
  char* pbuf = lds + 16384 + w * (16 * 144);

  const float scale = 0.044194173824159216f;

  short8 qa[2];
  {
    const unsigned short* Qg =
        Qb + ((size_t)bh * 1024 + q0 + w * 16 + lr) * 64 + ls * 8;
    qa[0] = *(const short8*)(Qg);
    qa[1] = *(const short8*)(Qg + 32);
  }

  f32x4 O[4] = {};
  float mrow[4], lrow[4];
#pragma unroll
  for (int r = 0; r < 4; ++r) { mrow[r] = -INFINITY; lrow[r] = 0.f; }

  const unsigned short* Kg = Kb + (size_t)bh * 1024 * 64;
  const char* Vg = (const char*)(Vt + (size_t)bh * 64 * 1024);

  for (int kc = 0; kc < 16; ++kc) {
    {
      int row = t >> 3;
      int c8  = (t & 7) * 8;
#pragma unroll
      for (int it = 0; it < 2; ++it) {
        int rr = row + it * 32;
        int4 kv = *(const int4*)(Kg + (size_t)(kc * 64 + rr) * 64 + c8);
        *(int4*)(kbuf + swz(rr, c8 * 2)) = kv;
        int swv = (rr & 7) << 4;
        int4 vv = *(const int4*)(Vg + (size_t)rr * 2048 + kc * 128 +
                                 ((c8 * 2) ^ swv));
        *(int4*)(vbuf + swz(rr, c8 * 2)) = vv;
      }
    }
    __syncthreads();

    f32x4 s[4] = {};
#pragma unroll
    for (int kk = 0; kk < 2; ++kk) {
#pragma unroll
      for (int nt = 0; nt < 4; ++nt) {
        short8 bk = *(const short8*)(kbuf + swz(nt * 16 + lr, kk * 64 + ls * 16));
        s[nt] = mfma_bf16(qa[kk], bk, s[nt]);
      }
    }

    float p[4][4];
    float cmax[4];
#pragma unroll
    for (int r = 0; r < 4; ++r) cmax[r] = -INFINITY;
#pragma unroll
    for (int nt = 0; nt < 4; ++nt)
#pragma unroll
      for (int r = 0; r < 4; ++r) {
        float sv = s[nt][r];
        p[nt][r] = (sv == 0.f) ? -INFINITY : sv * scale;
        cmax[r] = fmaxf(cmax[r], p[nt][r]);
      }
#pragma unroll
    for (int r = 0; r < 4; ++r)
#pragma unroll
      for (int off = 1; off < 16; off <<= 1)
        cmax[r] = fmaxf(cmax[r], __shfl_xor(cmax[r], off, 64));

    float alpha[4];
#pragma unroll
    for (int r = 0; r < 4; ++r) {
      float mnew = fmaxf(mrow[r], cmax[r]);
      alpha[r] = (mnew == -INFINITY) ? 1.f : exp2f((mrow[r] - mnew) * LOG2E);
      mrow[r] = mnew;
    }
    float lsum[4] = {0.f, 0.f, 0.f, 0.f};
#pragma unroll
    for (int nt = 0; nt < 4; ++nt)
#pragma unroll
      for (int r = 0; r < 4; ++r) {
        float pv = (p[nt][r] == -INFINITY)
                       ? 0.f
                       : exp2f((p[nt][r] - mrow[r]) * LOG2E);
        p[nt][r] = pv;
        lsum[r] += pv;
      }
#pragma unroll
    for (int r = 0; r < 4; ++r) {
#pragma unroll
      for (int off = 1; off < 16; off <<= 1)
        lsum[r] += __shfl_xor(lsum[r], off, 64);
      lrow[r] = lrow[r] * alpha[r] + lsum[r];
    }
#pragma unroll
    for (int dt = 0; dt < 4; ++dt)
#pragma unroll
      for (int r = 0; r < 4; ++r) O[dt][r] *= alpha[r];

#pragma unroll
    for (int nt = 0; nt < 4; ++nt)
#pragma unroll
      for (int r = 0; r < 4; ++r)
        *(unsigned short*)(pbuf + (ls * 4 + r) * 144 + (nt * 16 + lr) * 2) =
            f2bf(p[nt][r]);

#pragma unroll
    for (int kk = 0; kk < 2; ++kk) {
      short8 pa = *(const short8*)(pbuf + lr * 144 + kk * 64 + ls * 16);
#pragma unroll
      for (int dt = 0; dt < 4; ++dt) {
        short8 bv = *(const short8*)(vbuf + swz(dt * 16 + lr, kk * 64 + ls * 16));
        O[dt] = mfma_bf16(pa, bv, O[dt]);
      }
    }
    __syncthreads();
  }

  float rinv[4];
#pragma unroll
  for (int r = 0; r < 4; ++r) rinv[r] = (lrow[r] > 0.f) ? 1.f / lrow[r] : 0.f;
  const int b = bh >> 3, h = bh & 7;
#pragma unroll
  for (int dt = 0; dt < 4; ++dt)
#pragma unroll
    for (int r = 0; r < 4; ++r) {
      int n = q0 + w * 16 + ls * 4 + r;
      int c = h * 64 + dt * 16 + lr;
      V1[((size_t)b * 1024 + n) * 512 + c] = O[dt][r] * rinv[r];
    }
}

// ---------------------------------------------------------------------------
extern "C" void kernel_launch(void* const* d_in, const int* in_sizes, int n_in,
                              void* d_out, int out_size, void* d_ws,
                              size_t ws_size, hipStream_t stream) {
  const float* x1    = (const float*)d_in[0];
  const float* x2    = (const float*)d_in[1];
  const float* Wq    = (const float*)d_in[2];
  const float* Wk    = (const float*)d_in[3];
  const float* Wv    = (const float*)d_in[4];
  const float* gamma = (const float*)d_in[5];
  const float* beta  = (const float*)d_in[6];
  float* out = (float*)d_out;
  char* ws = (char*)d_ws;

  const size_t MB = 1u << 20;
  unsigned short* xb  = (unsigned short*)(ws);                 // 8 MB (dead after proj)
  unsigned short* Wqb = (unsigned short*)(ws + 8 * MB);
  unsigned short* Wkb = (unsigned short*)(ws + 8 * MB + 512 * 1024);
  unsigned short* Wvb = (unsigned short*)(ws + 9 * MB);
  unsigned short* Qb  = (unsigned short*)(ws + 10 * MB);       // 4 MB
  unsigned short* Kb  = (unsigned short*)(ws + 14 * MB);       // 4 MB
  void*           Vt  = (void*)(ws + 18 * MB);                 // 4 MB (bf16) / 2 MB (fp8)
  float*          Vf  = (float*)(ws + 22 * MB);                // 8 MB
  float*          V1a = (float*)(ws + 30 * MB);                // 8 MB
  float*          lsm = (float*)(ws + 38 * MB);                // 256 KB
  unsigned char*  Pm  = (unsigned char*)(ws + 39 * MB);        // 32 MB (fp8)
  float*          V1b = (float*)(ws);                          // reuse xb region

  const bool bigws = ws_size >= (size_t)71 * MB;

  k_convert_all<<<2560, 256, 0, stream>>>(x1, x2, Wq, Wk, Wv, xb, Wqb, Wkb,
                                          Wvb);
  k_proj<<<384, 256, 0, stream>>>(xb, Wqb, Wkb, Wvb, Qb, Kb, Vf);

  if (bigws) {
    k_transpose_v<<<dim3(16, 32), 256, 0, stream>>>(Vf, Vt, 1);
    k_scores<<<1024, 256, 0, stream>>>(Qb, Kb, Pm, lsm);
    for (int layer = 0; layer < 3; ++layer) {
      k_pv<<<1024, 256, 0, stream>>>(Pm, (const unsigned char*)Vt, lsm, V1a,
                                     V1b);
      if (layer < 2)
        k_ln_t<<<256, 256, 0, stream>>>(V1a, V1b, Vf, gamma, beta, Vf, Vt, 1);
      else
        k_ln_t<<<256, 256, 0, stream>>>(V1a, V1b, Vf, gamma, beta, out, Vt, 2);
    }
  } else {
    hipMemsetAsync(V1b, 0, 8 * MB, stream);
    k_transpose_v<<<dim3(16, 32), 256, 0, stream>>>(Vf, Vt, 0);
    for (int layer = 0; layer < 3; ++layer) {
      k_attn<<<dim3(16, 32), 256, 0, stream>>>(Qb, Kb,
                                               (const unsigned short*)Vt, V1a);
      if (layer < 2)
        k_ln_t<<<256, 256, 0, stream>>>(V1a, V1b, Vf, gamma, beta, Vf, Vt, 0);
      else
        k_ln_t<<<256, 256, 0, stream>>>(V1a, V1b, Vf, gamma, beta, out, Vt, 2);
    }
  }
}

// Round 11
// 136.245 us; speedup vs baseline: 1.0817x; 1.0817x over previous
//
#include <hip/hip_runtime.h>

// ---------------------------------------------------------------------------
// CrossModeAttention: B=4, N=1024, D1=D2=512, C=512, H=8, DH=64, LAYERS=3
// Q,K layer-invariant => P = exp(QK^T*scale) computed ONCE, fp8 e4m3 storage
// for P and Vt. R11: branchless fp8 convert + raw v_exp_f32 (k_scores was
// VALU-bound on the divergent subnormal branch in f2e4m3).
// ---------------------------------------------------------------------------

#define LOG2E 1.44269504088896f

using f32x4   = __attribute__((ext_vector_type(4))) float;
using short8  = __attribute__((ext_vector_type(8))) short;
using ushort8 = __attribute__((ext_vector_type(8))) unsigned short;
using uchar8  = __attribute__((ext_vector_type(8))) unsigned char;
using uchar16 = __attribute__((ext_vector_type(16))) unsigned char;

__device__ inline unsigned short f2bf(float f) {
  unsigned u = __builtin_bit_cast(unsigned, f);
  u += 0x7fffu + ((u >> 16) & 1u);   // RNE
  return (unsigned short)(u >> 16);
}
__device__ inline float bf2f(unsigned short h) {
  unsigned u = (unsigned)h << 16;
  return __builtin_bit_cast(float, u);
}

// f32 -> OCP e4m3fn, BRANCHLESS (~7 VALU): RNE to 3 mantissa bits; |f|<2^-6
// flushed to 0 (callers' values are never f32-subnormal; flush err <= 2^-6 on
// a sliver of inputs, averaged away by P·V); clamp to 448 (0x7E).
__device__ inline unsigned char f2e4m3_fast(float f) {
  unsigned u = __builtin_bit_cast(unsigned, f);
  unsigned sign = (u >> 24) & 0x80u;
  unsigned a = u & 0x7fffffffu;
  unsigned v = a + (0x7ffffu + ((a >> 20) & 1u));   // RNE
  unsigned m = (v >> 20) - 960u;                    // (E<<3)|M
  m = (m > 126u) ? 126u : m;                        // clamp at 448
  m = (a < 0x3c000000u) ? 0u : m;                   // flush tiny/zero
  return (unsigned char)(sign | m);
}

__device__ inline f32x4 mfma_bf16(short8 a, short8 b, f32x4 c) {
  return __builtin_amdgcn_mfma_f32_16x16x32_bf16(a, b, c, 0, 0, 0);
}

__device__ inline void gload_lds16(const void* g, void* l) {
  __builtin_amdgcn_global_load_lds(
      (const __attribute__((address_space(1))) unsigned int*)g,
      (__attribute__((address_space(3))) unsigned int*)l, 16, 0, 0);
}

// XOR swizzle for 128B-row LDS tiles (G4)
__device__ inline int swz(int row, int byte_in_row) {
  return row * 128 + (byte_in_row ^ ((row & 7) << 4));
}

// ---------------------------------------------------------------------------
// Merged convert: xb bf16 [4096][1024] from x1|x2, then Wq,Wk,Wv -> bf16.
// ---------------------------------------------------------------------------
__global__ __launch_bounds__(256) void k_convert_all(
    const float* __restrict__ x1, const float* __restrict__ x2,
    const float* __restrict__ Wq, const float* __restrict__ Wk,
    const float* __restrict__ Wv,
    unsigned short* __restrict__ xb, unsigned short* __restrict__ Wqb,
    unsigned short* __restrict__ Wkb, unsigned short* __restrict__ Wvb) {
  int i = blockIdx.x * 256 + threadIdx.x;
  const float* src;
  unsigned short* dst;
  if (i < 524288) {
    int e0 = i * 8, m = e0 >> 10, d = e0 & 1023;
    src = (d < 512) ? (x1 + (size_t)m * 512 + d)
                    : (x2 + (size_t)m * 512 + (d - 512));
    dst = xb + (size_t)e0;
  } else if (i < 557056) {
    int j = (i - 524288) * 8;
    src = Wq + j; dst = Wqb + j;
  } else if (i < 589824) {
    int j = (i - 557056) * 8;
    src = Wk + j; dst = Wkb + j;
  } else {
    int j = (i - 589824) * 8;
    src = Wv + j; dst = Wvb + j;
  }
  float4 a = ((const float4*)src)[0];
  float4 b = ((const float4*)src)[1];
  ushort8 o;
  o[0] = f2bf(a.x); o[1] = f2bf(a.y); o[2] = f2bf(a.z); o[3] = f2bf(a.w);
  o[4] = f2bf(b.x); o[5] = f2bf(b.y); o[6] = f2bf(b.z); o[7] = f2bf(b.w);
  *(ushort8*)dst = o;
}

// ---------------------------------------------------------------------------
// Projections: 128x128 tile, BK=64, global_load_lds. z=0 Q, z=1 K, z=2 V.
// ---------------------------------------------------------------------------
__global__ __launch_bounds__(256) void k_proj(
    const unsigned short* __restrict__ xb,
    const unsigned short* __restrict__ Wqb,
    const unsigned short* __restrict__ Wkb,
    const unsigned short* __restrict__ Wvb,
    unsigned short* __restrict__ Qb, unsigned short* __restrict__ Kb,
    float* __restrict__ Vf) {
  __shared__ __align__(16) unsigned short Atile[128 * 64];
  __shared__ __align__(16) unsigned short Btile[128 * 64];

  const int id  = blockIdx.x;
  const int z   = id % 3;
  const int rem = id / 3;
  const int c0  = (rem & 3) * 128;
  const int m0  = (rem >> 2) * 128;

  const int K    = (z == 2) ? 1024 : 512;
  const int aoff = (z == 1) ? 512 : 0;
  const unsigned short* W = (z == 0) ? Wqb : (z == 1) ? Wkb : Wvb;

  const int t  = threadIdx.x;
  const int w  = t >> 6, l = t & 63;
  const int lr = l & 15, ls = l >> 4;
  const int wr = w >> 1, wc = w & 1;

  const int srow  = l >> 3;
  const int scol8 = (l & 7) * 8;

  f32x4 acc[4][4] = {};

  for (int k0 = 0; k0 < K; k0 += 64) {
#pragma unroll
    for (int j = 0; j < 4; ++j) {
      int ch  = w * 4 + j;
      int row = ch * 8 + srow;
      gload_lds16(xb + (size_t)(m0 + row) * 1024 + aoff + k0 + scol8,
                  Atile + ch * 512);
      gload_lds16(W + (size_t)(c0 + row) * K + k0 + scol8,
                  Btile + ch * 512);
    }
    __syncthreads();
#pragma unroll
    for (int ks = 0; ks < 2; ++ks) {
      short8 af[4], bf[4];
#pragma unroll
      for (int mf = 0; mf < 4; ++mf)
        af[mf] = *(const short8*)(Atile + (wr * 64 + mf * 16 + lr) * 64 +
                                  ks * 32 + ls * 8);
#pragma unroll
      for (int nf = 0; nf < 4; ++nf)
        bf[nf] = *(const short8*)(Btile + (wc * 64 + nf * 16 + lr) * 64 +
                                  ks * 32 + ls * 8);
#pragma unroll
      for (int mf = 0; mf < 4; ++mf)
#pragma unroll
        for (int nf = 0; nf < 4; ++nf)
          acc[mf][nf] = mfma_bf16(af[mf], bf[nf], acc[mf][nf]);
    }
    __syncthreads();
  }

#pragma unroll
  for (int mf = 0; mf < 4; ++mf)
#pragma unroll
    for (int nf = 0; nf < 4; ++nf)
#pragma unroll
      for (int r = 0; r < 4; ++r) {
        int m = m0 + wr * 64 + mf * 16 + ls * 4 + r;
        int c = c0 + wc * 64 + nf * 16 + lr;
        float v = acc[mf][nf][r];
        if (z == 2) {
          Vf[(size_t)m * 512 + c] = v;
        } else {
          int b = m >> 10, n = m & 1023, h = c >> 6, dh = c & 63;
          size_t idx = ((size_t)(b * 8 + h) * 1024 + n) * 64 + dh;
          (z == 0 ? Qb : Kb)[idx] = f2bf(v);
        }
      }
}

// ---------------------------------------------------------------------------
// Transpose (initial): Vf f32 [B,N,512] -> Vt [B,H,64,N], swizzled in-block.
// mode 0: bf16 (2048B rows, fallback). mode 1: fp8 (1024B rows).
// ---------------------------------------------------------------------------
__global__ __launch_bounds__(256) void k_transpose_v(
    const float* __restrict__ Vf, void* __restrict__ Vt, int mode) {
  __shared__ unsigned short tile[64 * 66];
  const int bh = blockIdx.y;
  const int b = bh >> 3, h = bh & 7;
  const int n0 = blockIdx.x * 64;
  const int t = threadIdx.x;
  {
    int n = t >> 2, dh0 = (t & 3) * 16;
    const float* src = Vf + ((size_t)b * 1024 + n0 + n) * 512 + h * 64 + dh0;
    unsigned short* dst = tile + n * 66 + dh0;
#pragma unroll
    for (int j = 0; j < 16; j += 4) {
      float4 v = *(const float4*)(src + j);
      dst[j + 0] = f2bf(v.x); dst[j + 1] = f2bf(v.y);
      dst[j + 2] = f2bf(v.z); dst[j + 3] = f2bf(v.w);
    }
  }
  __syncthreads();
#pragma unroll
  for (int it = 0; it < 2; ++it) {
    int dh = (t >> 3) + it * 32, n8 = (t & 7) * 8;
    if (mode == 0) {
      ushort8 o;
#pragma unroll
      for (int j = 0; j < 8; ++j) o[j] = tile[(n8 + j) * 66 + dh];
      char* dst = (char*)Vt + ((size_t)(bh * 64 + dh)) * 2048 + n0 * 2 +
                  ((n8 * 2) ^ ((dh & 7) << 4));
      *(ushort8*)dst = o;
    } else {
      uchar8 o;
#pragma unroll
      for (int j = 0; j < 8; ++j)
        o[j] = f2e4m3_fast(bf2f(tile[(n8 + j) * 66 + dh]));
      int byte = n0 + n8;
      char* dst = (char*)Vt + ((size_t)(bh * 64 + dh)) * 1024 + (byte & ~127) +
                  ((byte & 127) ^ ((dh & 7) << 4));
      *(uchar8*)dst = o;
    }
  }
}

// ---------------------------------------------------------------------------
// k_scores: P = exp(QK^T*scale) -> FP8 e4m3, masked (s==0 -> 0). Grid 1024
// XCD-chunked: head = lid>>5, qtile = (lid>>1)&15, khalf = lid&1.
// P fp8 [32][1024][1024B], swizzled within each 128B block (byte ^ (n&7)<<4).
// Partial row sums (f32, pre-rounding) -> lsm[khalf][32][1024].
// ---------------------------------------------------------------------------
__global__ __launch_bounds__(256) void k_scores(
    const unsigned short* __restrict__ Qb,
    const unsigned short* __restrict__ Kb,
    unsigned char* __restrict__ Pmat, float* __restrict__ lsum_g) {
  __shared__ char lds[8192 + 4 * 16 * 80];
  char* kbuf = lds;
  const int id  = blockIdx.x;
  const int lid = (id & 7) * 128 + (id >> 3);
  const int bh  = lid >> 5;
  const int q0  = ((lid >> 1) & 15) * 64;
  const int kh  = lid & 1;
  const int t = threadIdx.x;
  const int w = t >> 6, l = t & 63, lr = l & 15, ls = l >> 4;
  char* pbuf = lds + 8192 + w * (16 * 80);

  const float sclog2e = 0.0637587160f;   // (512^-0.5) * log2(e)

  short8 qa[2];
  {
    const unsigned short* Qg =
        Qb + ((size_t)bh * 1024 + q0 + w * 16 + lr) * 64 + ls * 8;
    qa[0] = *(const short8*)(Qg);
    qa[1] = *(const short8*)(Qg + 32);
  }

  const unsigned short* Kg = Kb + (size_t)bh * 1024 * 64 + kh * 512 * 64;
  unsigned char* Pg = Pmat + (size_t)bh * 1024 * 1024;

  float lacc[4] = {0.f, 0.f, 0.f, 0.f};

  const int srow = t >> 3, sc8 = (t & 7) * 8;
  int4 kreg[2];
  kreg[0] = *(const int4*)(Kg + (size_t)(srow)*64 + sc8);
  kreg[1] = *(const int4*)(Kg + (size_t)(srow + 32) * 64 + sc8);

  for (int kc = 0; kc < 8; ++kc) {
    *(int4*)(kbuf + swz(srow, sc8 * 2)) = kreg[0];
    *(int4*)(kbuf + swz(srow + 32, sc8 * 2)) = kreg[1];
    __syncthreads();
    if (kc < 7) {
      kreg[0] = *(const int4*)(Kg + (size_t)((kc + 1) * 64 + srow) * 64 + sc8);
      kreg[1] = *(const int4*)(Kg + (size_t)((kc + 1) * 64 + srow + 32) * 64 + sc8);
    }

    f32x4 s[4] = {};
#pragma unroll
    for (int kk = 0; kk < 2; ++kk) {
#pragma unroll
      for (int nt = 0; nt < 4; ++nt) {
        short8 bk = *(const short8*)(kbuf + swz(nt * 16 + lr, kk * 64 + ls * 16));
        s[nt] = mfma_bf16(qa[kk], bk, s[nt]);
      }
    }

    // p = exp2(s*c) masked; raw v_exp_f32 + branchless fp8 cvt (R11)
#pragma unroll
    for (int nt = 0; nt < 4; ++nt)
#pragma unroll
      for (int r = 0; r < 4; ++r) {
        float sv = s[nt][r];
        float pv = (sv == 0.f) ? 0.f : __builtin_amdgcn_exp2f(sv * sclog2e);
        lacc[r] += pv;
        pbuf[(ls * 4 + r) * 80 + nt * 16 + lr] = (char)f2e4m3_fast(pv);
      }

    // write-out: wave tile = 16 rows x 64B; lane -> (prow = l>>2, pchk = l&3)
    int gkc = kh * 8 + kc;
    {
      int prow = l >> 2, pchk = l & 3;
      uchar16 pv16 = *(const uchar16*)(pbuf + prow * 80 + pchk * 16);
      int n = q0 + w * 16 + prow;
      *(uchar16*)(Pg + (size_t)n * 1024 + (gkc >> 1) * 128 +
                  (((gkc & 1) * 64 + pchk * 16) ^ ((n & 7) << 4))) = pv16;
    }
    __syncthreads();
  }

#pragma unroll
  for (int r = 0; r < 4; ++r) {
#pragma unroll
    for (int off = 1; off < 16; off <<= 1)
      lacc[r] += __shfl_xor(lacc[r], off, 64);
  }
  if (lr == 0) {
#pragma unroll
    for (int r = 0; r < 4; ++r)
      lsum_g[kh * 32768 + (size_t)bh * 1024 + q0 + w * 16 + ls * 4 + r] =
          lacc[r];
  }
}

// ---------------------------------------------------------------------------
// k_pv: fp8 x fp8 MFMA. V1h[n, h*64+dh] = (1/l[n]) * sum_{m half} P[n,m]*V[dh,m].
// BK=128 fp8 elements (128B rows), 4 iterations, gload_lds 2-phase dbuf.
// Grid 1024 XCD-chunked: head = lid>>5, ntile = (lid>>1)&15, mhalf = lid&1.
// ---------------------------------------------------------------------------
__global__ __launch_bounds__(256) void k_pv(
    const unsigned char* __restrict__ Pmat,
    const unsigned char* __restrict__ Vt,
    const float* __restrict__ lsum_g, float* __restrict__ V1a,
    float* __restrict__ V1b) {
  __shared__ __align__(16) char Ab[2][8192];
  __shared__ __align__(16) char Bb[2][8192];
  const int id  = blockIdx.x;
  const int lid = (id & 7) * 128 + (id >> 3);
  const int head = lid >> 5;
  const int n0   = ((lid >> 1) & 15) * 64;
  const int mh   = lid & 1;
  const int t = threadIdx.x;
  const int w = t >> 6, l = t & 63, lr = l & 15, ls = l >> 4;

  const char* Pg = (const char*)(Pmat + (size_t)head * 1024 * 1024) +
                   (size_t)n0 * 1024 + mh * 512;
  const char* Vg = (const char*)(Vt + (size_t)head * 64 * 1024) + mh * 512;

  const int srow = w * 16 + (l >> 3);
  const int sc16 = (l & 7) * 16;

  f32x4 acc[4] = {};

  auto STAGE = [&](int buf, int kc) {
#pragma unroll
    for (int j = 0; j < 2; ++j) {
      int row = srow + j * 8;
      gload_lds16(Pg + (size_t)row * 1024 + kc * 128 + sc16,
                  &Ab[buf][w * 2048 + j * 1024]);
      gload_lds16(Vg + (size_t)row * 1024 + kc * 128 + sc16,
                  &Bb[buf][w * 2048 + j * 1024]);
    }
  };

  STAGE(0, 0);
  __syncthreads();
  int cur = 0;
  for (int kc = 0; kc < 4; ++kc) {
    if (kc < 3) STAGE(cur ^ 1, kc + 1);
#pragma unroll
    for (int ks = 0; ks < 4; ++ks) {
      long af = *(const long*)(&Ab[cur][swz(w * 16 + lr, ks * 32 + ls * 8)]);
#pragma unroll
      for (int nf = 0; nf < 4; ++nf) {
        long bf8 = *(const long*)(&Bb[cur][swz(nf * 16 + lr, ks * 32 + ls * 8)]);
        acc[nf] = __builtin_amdgcn_mfma_f32_16x16x32_fp8_fp8(af, bf8, acc[nf],
                                                             0, 0, 0);
      }
    }
    __syncthreads();
    cur ^= 1;
  }

  float* V1 = mh ? V1b : V1a;
  const int b = head >> 3, h = head & 7;
#pragma unroll
  for (int r = 0; r < 4; ++r) {
    int n = n0 + w * 16 + ls * 4 + r;
    float lv = lsum_g[(size_t)head * 1024 + n] +
               lsum_g[32768 + (size_t)head * 1024 + n];
    float rinv = (lv > 0.f) ? 1.f / lv : 0.f;
#pragma unroll
    for (int nf = 0; nf < 4; ++nf)
      V1[((size_t)b * 1024 + n) * 512 + h * 64 + nf * 16 + lr] =
          acc[nf][r] * rinv;
  }
}

// ---------------------------------------------------------------------------
// Fused LayerNorm (+ optional transpose): y = LN(V1a+V1b+Vf).
// mode 0: bf16 Vt (fallback). mode 1: fp8 Vt. mode 2: no Vt (final layer).
// ---------------------------------------------------------------------------
__global__ __launch_bounds__(256) void k_ln_t(
    const float* __restrict__ V1a, const float* __restrict__ V1b,
    const float* __restrict__ Vf_in,
    const float* __restrict__ gamma, const float* __restrict__ beta,
    float* __restrict__ Vf_out, void* __restrict__ Vt, int mode) {
  __shared__ unsigned short tile[16 * 520];
  const int blk = blockIdx.x;
  const int b  = blk >> 6;
  const int n0 = (blk & 63) * 16;
  const int t = threadIdx.x;
  const int row = t >> 4;
  const int c0  = (t & 15) * 32;
  const size_t base = ((size_t)b * 1024 + n0 + row) * 512 + c0;

  float x[32];
  float s = 0.f, sq = 0.f;
#pragma unroll
  for (int j = 0; j < 32; j += 4) {
    float4 a0 = *(const float4*)(V1a + base + j);
    float4 a1 = *(const float4*)(V1b + base + j);
    float4 v = *(const float4*)(Vf_in + base + j);
    float4 y = {a0.x + a1.x + v.x, a0.y + a1.y + v.y, a0.z + a1.z + v.z,
                a0.w + a1.w + v.w};
    x[j + 0] = y.x; x[j + 1] = y.y; x[j + 2] = y.z; x[j + 3] = y.w;
    s  += y.x + y.y + y.z + y.w;
    sq += y.x * y.x + y.y * y.y + y.z * y.z + y.w * y.w;
  }
#pragma unroll
  for (int off = 1; off < 16; off <<= 1) {
    s  += __shfl_xor(s, off, 64);
    sq += __shfl_xor(sq, off, 64);
  }
  float mu   = s * (1.f / 512.f);
  float var  = sq * (1.f / 512.f) - mu * mu;
  float rstd = rsqrtf(var + 1e-5f);

  unsigned short* trow = tile + row * 520 + c0;
#pragma unroll
  for (int j = 0; j < 32; j += 4) {
    float4 g = *(const float4*)(gamma + c0 + j);
    float4 bb = *(const float4*)(beta + c0 + j);
    float4 y;
    y.x = (x[j + 0] - mu) * rstd * g.x + bb.x;
    y.y = (x[j + 1] - mu) * rstd * g.y + bb.y;
    y.z = (x[j + 2] - mu) * rstd * g.z + bb.z;
    y.w = (x[j + 3] - mu) * rstd * g.w + bb.w;
    *(float4*)(Vf_out + base + j) = y;
    if (mode != 2) {
      trow[j + 0] = f2bf(y.x); trow[j + 1] = f2bf(y.y);
      trow[j + 2] = f2bf(y.z); trow[j + 3] = f2bf(y.w);
    }
  }
  if (mode == 2) return;
  __syncthreads();

#pragma unroll
  for (int it = 0; it < 2; ++it) {
    int d = t + it * 256;
    int h = d >> 6, dh = d & 63;
    int sw = (dh & 7) << 4;
    if (mode == 0) {
      ushort8 o0, o1;
#pragma unroll
      for (int j = 0; j < 8; ++j) {
        o0[j] = tile[j * 520 + d];
        o1[j] = tile[(j + 8) * 520 + d];
      }
      int byte0 = n0 * 2;
      char* rowb = (char*)Vt + ((size_t)((b * 8 + h) * 64 + dh)) * 2048 +
                   (byte0 & ~127);
      *(ushort8*)(rowb + ((byte0 & 127) ^ sw)) = o0;
      *(ushort8*)(rowb + (((byte0 & 127) + 16) ^ sw)) = o1;
    } else {
      uchar16 o;
#pragma unroll
      for (int j = 0; j < 16; ++j) o[j] = f2e4m3_fast(bf2f(tile[j * 520 + d]));
      char* rowb = (char*)Vt + ((size_t)((b * 8 + h) * 64 + dh)) * 1024 +
                   (n0 & ~127);
      *(uchar16*)(rowb + ((n0 & 127) ^ sw)) = o;
    }
  }
}

// ---------------------------------------------------------------------------
// Fallback fused flash attention (ws too small only; bf16 Vt mode 0)
// ---------------------------------------------------------------------------
__global__ __launch_bounds__(256) void k_attn(
    const unsigned short* __restrict__ Qb,
    const unsigned short* __restrict__ Kb,
    const unsigned short* __restrict__ Vt,
    float* __restrict__ V1) {
  __shared__ char lds[8192 + 8192 + 4 * 16 * 144];
  char* kbuf = lds;
  char* vbuf = lds + 8192;
  const int bh = blockIdx.y;
  const int q0 = blockIdx.x * 64;
  const int t = threadIdx.x;
  const int w = t >> 6, l = t & 63, lr = l & 15, ls = l >> 4;
  char* pbuf = lds + 16384 + w * (16 * 144);

  const float scale = 0.044194173824159216f;

  short8 qa[2];
  {
    const unsigned short* Qg =
        Qb + ((size_t)bh * 1024 + q0 + w * 16 + lr) * 64 + ls * 8;
    qa[0] = *(const short8*)(Qg);
    qa[1] = *(const short8*)(Qg + 32);
  }

  f32x4 O[4] = {};
  float mrow[4], lrow[4];
#pragma unroll
  for (int r = 0; r < 4; ++r) { mrow[r] = -INFINITY; lrow[r] = 0.f; }

  const unsigned short* Kg = Kb + (size_t)bh * 1024 * 64;
  const char* Vg = (const char*)(Vt + (size_t)bh * 64 * 1024);

  for (int kc = 0; kc < 16; ++kc) {
    {
      int row = t >> 3;
      int c8  = (t & 7) * 8;
#pragma unroll
      for (int it = 0; it < 2; ++it) {
        int rr = row + it * 32;
        int4 kv = *(const int4*)(Kg + (size_t)(kc * 64 + rr) * 64 + c8);
        *(int4*)(kbuf + swz(rr, c8 * 2)) = kv;
        int swv = (rr & 7) << 4;
        int4 vv = *(const int4*)(Vg + (size_t)rr * 2048 + kc * 128 +
                                 ((c8 * 2) ^ swv));
        *(int4*)(vbuf + swz(rr, c8 * 2)) = vv;
      }
    }
    __syncthreads();

    f32x4 s[4] = {};
#pragma unroll
    for (int kk = 0; kk < 2; ++kk) {
#pragma unroll
      for (int nt = 0; nt < 4; ++nt) {
        short8 bk = *(const short8*)(kbuf + swz(nt * 16 + lr, kk * 64 + ls * 16));
        s[nt] = mfma_bf16(qa[kk], bk, s[nt]);
      }
    }

    float p[4][4];
    float cmax[4];
#pragma unroll
    for (int r = 0; r < 4; ++r) cmax[r] = -INFINITY;
#pragma unroll
    for (int nt = 0; nt < 4; ++nt)
#pragma unroll
      for (int r = 0; r < 4; ++r) {
        float sv = s[nt][r];
        p[nt][r] = (sv == 0.f) ? -INFINITY : sv * scale;
        cmax[r] = fmaxf(cmax[r], p[nt][r]);
      }
#pragma unroll
    for (int r = 0; r < 4; ++r)
#pragma unroll
      for (int off = 1; off < 16; off <<= 1)
        cmax[r] = fmaxf(cmax[r], __shfl_xor(cmax[r], off, 64));

    float alpha[4];
#pragma unroll
    for (int r = 0; r < 4; ++r) {
      float mnew = fmaxf(mrow[r], cmax[r]);
      alpha[r] = (mnew == -INFINITY) ? 1.f : exp2f((mrow[r] - mnew) * LOG2E);
      mrow[r] = mnew;
    }
    float lsum[4] = {0.f, 0.f, 0.f, 0.f};
#pragma unroll
    for (int nt = 0; nt < 4; ++nt)
#pragma unroll
      for (int r = 0; r < 4; ++r) {
        float pv = (p[nt][r] == -INFINITY)
                       ? 0.f
                       : exp2f((p[nt][r] - mrow[r]) * LOG2E);
        p[nt][r] = pv;
        lsum[r] += pv;
      }
#pragma unroll
    for (int r = 0; r < 4; ++r) {
#pragma unroll
      for (int off = 1; off < 16; off <<= 1)
        lsum[r] += __shfl_xor(lsum[r], off, 64);
      lrow[r] = lrow[r] * alpha[r] + lsum[r];
    }
#pragma unroll
    for (int dt = 0; dt < 4; ++dt)
#pragma unroll
      for (int r = 0; r < 4; ++r) O[dt][r] *= alpha[r];

#pragma unroll
    for (int nt = 0; nt < 4; ++nt)
#pragma unroll
      for (int r = 0; r < 4; ++r)
        *(unsigned short*)(pbuf + (ls * 4 + r) * 144 + (nt * 16 + lr) * 2) =
            f2bf(p[nt][r]);

#pragma unroll
    for (int kk = 0; kk < 2; ++kk) {
      short8 pa = *(const short8*)(pbuf + lr * 144 + kk * 64 + ls * 16);
#pragma unroll
      for (int dt = 0; dt < 4; ++dt) {
        short8 bv = *(const short8*)(vbuf + swz(dt * 16 + lr, kk * 64 + ls * 16));
        O[dt] = mfma_bf16(pa, bv, O[dt]);
      }
    }
    __syncthreads();
  }

  float rinv[4];
#pragma unroll
  for (int r = 0; r < 4; ++r) rinv[r] = (lrow[r] > 0.f) ? 1.f / lrow[r] : 0.f;
  const int b = bh >> 3, h = bh & 7;
#pragma unroll
  for (int dt = 0; dt < 4; ++dt)
#pragma unroll
    for (int r = 0; r < 4; ++r) {
      int n = q0 + w * 16 + ls * 4 + r;
      int c = h * 64 + dt * 16 + lr;
      V1[((size_t)b * 1024 + n) * 512 + c] = O[dt][r] * rinv[r];
    }
}

// ---------------------------------------------------------------------------
extern "C" void kernel_launch(void* const* d_in, const int* in_sizes, int n_in,
                              void* d_out, int out_size, void* d_ws,
                              size_t ws_size, hipStream_t stream) {
  const float* x1    = (const float*)d_in[0];
  const float* x2    = (const float*)d_in[1];
  const float* Wq    = (const float*)d_in[2];
  const float* Wk    = (const float*)d_in[3];
  const float* Wv    = (const float*)d_in[4];
  const float* gamma = (const float*)d_in[5];
  const float* beta  = (const float*)d_in[6];
  float* out = (float*)d_out;
  char* ws = (char*)d_ws;

  const size_t MB = 1u << 20;
  unsigned short* xb  = (unsigned short*)(ws);                 // 8 MB (dead after proj)
  unsigned short* Wqb = (unsigned short*)(ws + 8 * MB);
  unsigned short* Wkb = (unsigned short*)(ws + 8 * MB + 512 * 1024);
  unsigned short* Wvb = (unsigned short*)(ws + 9 * MB);
  unsigned short* Qb  = (unsigned short*)(ws + 10 * MB);       // 4 MB
  unsigned short* Kb  = (unsigned short*)(ws + 14 * MB);       // 4 MB
  void*           Vt  = (void*)(ws + 18 * MB);                 // 4 MB (bf16) / 2 MB (fp8)
  float*          Vf  = (float*)(ws + 22 * MB);                // 8 MB
  float*          V1a = (float*)(ws + 30 * MB);                // 8 MB
  float*          lsm = (float*)(ws + 38 * MB);                // 256 KB
  unsigned char*  Pm  = (unsigned char*)(ws + 39 * MB);        // 32 MB (fp8)
  float*          V1b = (float*)(ws);                          // reuse xb region

  const bool bigws = ws_size >= (size_t)71 * MB;

  k_convert_all<<<2560, 256, 0, stream>>>(x1, x2, Wq, Wk, Wv, xb, Wqb, Wkb,
                                          Wvb);
  k_proj<<<384, 256, 0, stream>>>(xb, Wqb, Wkb, Wvb, Qb, Kb, Vf);

  if (bigws) {
    k_transpose_v<<<dim3(16, 32), 256, 0, stream>>>(Vf, Vt, 1);
    k_scores<<<1024, 256, 0, stream>>>(Qb, Kb, Pm, lsm);
    for (int layer = 0; layer < 3; ++layer) {
      k_pv<<<1024, 256, 0, stream>>>(Pm, (const unsigned char*)Vt, lsm, V1a,
                                     V1b);
      if (layer < 2)
        k_ln_t<<<256, 256, 0, stream>>>(V1a, V1b, Vf, gamma, beta, Vf, Vt, 1);
      else
        k_ln_t<<<256, 256, 0, stream>>>(V1a, V1b, Vf, gamma, beta, out, Vt, 2);
    }
  } else {
    hipMemsetAsync(V1b, 0, 8 * MB, stream);
    k_transpose_v<<<dim3(16, 32), 256, 0, stream>>>(Vf, Vt, 0);
    for (int layer = 0; layer < 3; ++layer) {
      k_attn<<<dim3(16, 32), 256, 0, stream>>>(Qb, Kb,
                                               (const unsigned short*)Vt, V1a);
      if (layer < 2)
        k_ln_t<<<256, 256, 0, stream>>>(V1a, V1b, Vf, gamma, beta, Vf, Vt, 0);
      else
        k_ln_t<<<256, 256, 0, stream>>>(V1a, V1b, Vf, gamma, beta, out, Vt, 2);
    }
  }
}

// Round 12
// 125.845 us; speedup vs baseline: 1.1711x; 1.0826x over previous
//
#include <hip/hip_runtime.h>

// ---------------------------------------------------------------------------
// CrossModeAttention: B=4, N=1024, D1=D2=512, C=512, H=8, DH=64, LAYERS=3
// Q,K layer-invariant => P = exp(QK^T*scale) computed ONCE, fp8 e4m3 storage.
// R12: k_scores K-split x4 (grid 2048) + kbuf double-buffer (1 barrier/iter);
// k_ln_t grid 256->1024 (wave-per-row). Both were occupancy/latency-bound.
// ---------------------------------------------------------------------------

#define LOG2E 1.44269504088896f

using f32x4   = __attribute__((ext_vector_type(4))) float;
using short8  = __attribute__((ext_vector_type(8))) short;
using ushort8 = __attribute__((ext_vector_type(8))) unsigned short;
using ushort4v= __attribute__((ext_vector_type(4))) unsigned short;
using uchar8  = __attribute__((ext_vector_type(8))) unsigned char;
using uchar4v = __attribute__((ext_vector_type(4))) unsigned char;
using uchar16 = __attribute__((ext_vector_type(16))) unsigned char;

__device__ inline unsigned short f2bf(float f) {
  unsigned u = __builtin_bit_cast(unsigned, f);
  u += 0x7fffu + ((u >> 16) & 1u);   // RNE
  return (unsigned short)(u >> 16);
}
__device__ inline float bf2f(unsigned short h) {
  unsigned u = (unsigned)h << 16;
  return __builtin_bit_cast(float, u);
}

// f32 -> OCP e4m3fn, branchless (~7 VALU); |f|<2^-6 flushed to 0; clamp 448.
__device__ inline unsigned char f2e4m3_fast(float f) {
  unsigned u = __builtin_bit_cast(unsigned, f);
  unsigned sign = (u >> 24) & 0x80u;
  unsigned a = u & 0x7fffffffu;
  unsigned v = a + (0x7ffffu + ((a >> 20) & 1u));   // RNE
  unsigned m = (v >> 20) - 960u;                    // (E<<3)|M
  m = (m > 126u) ? 126u : m;                        // clamp at 448
  m = (a < 0x3c000000u) ? 0u : m;                   // flush tiny/zero
  return (unsigned char)(sign | m);
}

__device__ inline f32x4 mfma_bf16(short8 a, short8 b, f32x4 c) {
  return __builtin_amdgcn_mfma_f32_16x16x32_bf16(a, b, c, 0, 0, 0);
}

__device__ inline void gload_lds16(const void* g, void* l) {
  __builtin_amdgcn_global_load_lds(
      (const __attribute__((address_space(1))) unsigned int*)g,
      (__attribute__((address_space(3))) unsigned int*)l, 16, 0, 0);
}

// XOR swizzle for 128B-row LDS tiles (G4)
__device__ inline int swz(int row, int byte_in_row) {
  return row * 128 + (byte_in_row ^ ((row & 7) << 4));
}

// ---------------------------------------------------------------------------
// Merged convert: xb bf16 [4096][1024] from x1|x2, then Wq,Wk,Wv -> bf16.
// ---------------------------------------------------------------------------
__global__ __launch_bounds__(256) void k_convert_all(
    const float* __restrict__ x1, const float* __restrict__ x2,
    const float* __restrict__ Wq, const float* __restrict__ Wk,
    const float* __restrict__ Wv,
    unsigned short* __restrict__ xb, unsigned short* __restrict__ Wqb,
    unsigned short* __restrict__ Wkb, unsigned short* __restrict__ Wvb) {
  int i = blockIdx.x * 256 + threadIdx.x;
  const float* src;
  unsigned short* dst;
  if (i < 524288) {
    int e0 = i * 8, m = e0 >> 10, d = e0 & 1023;
    src = (d < 512) ? (x1 + (size_t)m * 512 + d)
                    : (x2 + (size_t)m * 512 + (d - 512));
    dst = xb + (size_t)e0;
  } else if (i < 557056) {
    int j = (i - 524288) * 8;
    src = Wq + j; dst = Wqb + j;
  } else if (i < 589824) {
    int j = (i - 557056) * 8;
    src = Wk + j; dst = Wkb + j;
  } else {
    int j = (i - 589824) * 8;
    src = Wv + j; dst = Wvb + j;
  }
  float4 a = ((const float4*)src)[0];
  float4 b = ((const float4*)src)[1];
  ushort8 o;
  o[0] = f2bf(a.x); o[1] = f2bf(a.y); o[2] = f2bf(a.z); o[3] = f2bf(a.w);
  o[4] = f2bf(b.x); o[5] = f2bf(b.y); o[6] = f2bf(b.z); o[7] = f2bf(b.w);
  *(ushort8*)dst = o;
}

// ---------------------------------------------------------------------------
// Projections: 128x128 tile, BK=64, global_load_lds. z=0 Q, z=1 K, z=2 V.
// ---------------------------------------------------------------------------
__global__ __launch_bounds__(256) void k_proj(
    const unsigned short* __restrict__ xb,
    const unsigned short* __restrict__ Wqb,
    const unsigned short* __restrict__ Wkb,
    const unsigned short* __restrict__ Wvb,
    unsigned short* __restrict__ Qb, unsigned short* __restrict__ Kb,
    float* __restrict__ Vf) {
  __shared__ __align__(16) unsigned short Atile[128 * 64];
  __shared__ __align__(16) unsigned short Btile[128 * 64];

  const int id  = blockIdx.x;
  const int z   = id % 3;
  const int rem = id / 3;
  const int c0  = (rem & 3) * 128;
  const int m0  = (rem >> 2) * 128;

  const int K    = (z == 2) ? 1024 : 512;
  const int aoff = (z == 1) ? 512 : 0;
  const unsigned short* W = (z == 0) ? Wqb : (z == 1) ? Wkb : Wvb;

  const int t  = threadIdx.x;
  const int w  = t >> 6, l = t & 63;
  const int lr = l & 15, ls = l >> 4;
  const int wr = w >> 1, wc = w & 1;

  const int srow  = l >> 3;
  const int scol8 = (l & 7) * 8;

  f32x4 acc[4][4] = {};

  for (int k0 = 0; k0 < K; k0 += 64) {
#pragma unroll
    for (int j = 0; j < 4; ++j) {
      int ch  = w * 4 + j;
      int row = ch * 8 + srow;
      gload_lds16(xb + (size_t)(m0 + row) * 1024 + aoff + k0 + scol8,
                  Atile + ch * 512);
      gload_lds16(W + (size_t)(c0 + row) * K + k0 + scol8,
                  Btile + ch * 512);
    }
    __syncthreads();
#pragma unroll
    for (int ks = 0; ks < 2; ++ks) {
      short8 af[4], bf[4];
#pragma unroll
      for (int mf = 0; mf < 4; ++mf)
        af[mf] = *(const short8*)(Atile + (wr * 64 + mf * 16 + lr) * 64 +
                                  ks * 32 + ls * 8);
#pragma unroll
      for (int nf = 0; nf < 4; ++nf)
        bf[nf] = *(const short8*)(Btile + (wc * 64 + nf * 16 + lr) * 64 +
                                  ks * 32 + ls * 8);
#pragma unroll
      for (int mf = 0; mf < 4; ++mf)
#pragma unroll
        for (int nf = 0; nf < 4; ++nf)
          acc[mf][nf] = mfma_bf16(af[mf], bf[nf], acc[mf][nf]);
    }
    __syncthreads();
  }

#pragma unroll
  for (int mf = 0; mf < 4; ++mf)
#pragma unroll
    for (int nf = 0; nf < 4; ++nf)
#pragma unroll
      for (int r = 0; r < 4; ++r) {
        int m = m0 + wr * 64 + mf * 16 + ls * 4 + r;
        int c = c0 + wc * 64 + nf * 16 + lr;
        float v = acc[mf][nf][r];
        if (z == 2) {
          Vf[(size_t)m * 512 + c] = v;
        } else {
          int b = m >> 10, n = m & 1023, h = c >> 6, dh = c & 63;
          size_t idx = ((size_t)(b * 8 + h) * 1024 + n) * 64 + dh;
          (z == 0 ? Qb : Kb)[idx] = f2bf(v);
        }
      }
}

// ---------------------------------------------------------------------------
// Transpose (initial): Vf f32 [B,N,512] -> Vt [B,H,64,N], swizzled in-block.
// mode 0: bf16 (2048B rows, fallback). mode 1: fp8 (1024B rows).
// ---------------------------------------------------------------------------
__global__ __launch_bounds__(256) void k_transpose_v(
    const float* __restrict__ Vf, void* __restrict__ Vt, int mode) {
  __shared__ unsigned short tile[64 * 66];
  const int bh = blockIdx.y;
  const int b = bh >> 3, h = bh & 7;
  const int n0 = blockIdx.x * 64;
  const int t = threadIdx.x;
  {
    int n = t >> 2, dh0 = (t & 3) * 16;
    const float* src = Vf + ((size_t)b * 1024 + n0 + n) * 512 + h * 64 + dh0;
    unsigned short* dst = tile + n * 66 + dh0;
#pragma unroll
    for (int j = 0; j < 16; j += 4) {
      float4 v = *(const float4*)(src + j);
      dst[j + 0] = f2bf(v.x); dst[j + 1] = f2bf(v.y);
      dst[j + 2] = f2bf(v.z); dst[j + 3] = f2bf(v.w);
    }
  }
  __syncthreads();
#pragma unroll
  for (int it = 0; it < 2; ++it) {
    int dh = (t >> 3) + it * 32, n8 = (t & 7) * 8;
    if (mode == 0) {
      ushort8 o;
#pragma unroll
      for (int j = 0; j < 8; ++j) o[j] = tile[(n8 + j) * 66 + dh];
      char* dst = (char*)Vt + ((size_t)(bh * 64 + dh)) * 2048 + n0 * 2 +
                  ((n8 * 2) ^ ((dh & 7) << 4));
      *(ushort8*)dst = o;
    } else {
      uchar8 o;
#pragma unroll
      for (int j = 0; j < 8; ++j)
        o[j] = f2e4m3_fast(bf2f(tile[(n8 + j) * 66 + dh]));
      int byte = n0 + n8;
      char* dst = (char*)Vt + ((size_t)(bh * 64 + dh)) * 1024 + (byte & ~127) +
                  ((byte & 127) ^ ((dh & 7) << 4));
      *(uchar8*)dst = o;
    }
  }
}

// ---------------------------------------------------------------------------
// k_scores: P = exp(QK^T*scale) -> FP8 e4m3, masked (s==0 -> 0).
// R12: grid 2048 XCD-chunked (head = lid>>6, qtile = (lid>>2)&15, kquarter =
// lid&3, 4 kc-chunks each); kbuf double-buffered -> ONE barrier per kc.
// P fp8 [32][1024][1024B], swizzled within each 128B block.
// Partial row sums -> lsm[kq][32][1024].
// ---------------------------------------------------------------------------
__global__ __launch_bounds__(256) void k_scores(
    const unsigned short* __restrict__ Qb,
    const unsigned short* __restrict__ Kb,
    unsigned char* __restrict__ Pmat, float* __restrict__ lsum_g) {
  __shared__ char lds[2 * 8192 + 4 * 16 * 80];
  char* kbuf0 = lds;
  char* kbuf1 = lds + 8192;
  const int id  = blockIdx.x;
  const int lid = (id & 7) * 256 + (id >> 3);
  const int bh  = lid >> 6;
  const int q0  = ((lid >> 2) & 15) * 64;
  const int kq  = lid & 3;
  const int t = threadIdx.x;
  const int w = t >> 6, l = t & 63, lr = l & 15, ls = l >> 4;
  char* pbuf = lds + 16384 + w * (16 * 80);

  const float sclog2e = 0.0637587160f;   // (512^-0.5) * log2(e)

  short8 qa[2];
  {
    const unsigned short* Qg =
        Qb + ((size_t)bh * 1024 + q0 + w * 16 + lr) * 64 + ls * 8;
    qa[0] = *(const short8*)(Qg);
    qa[1] = *(const short8*)(Qg + 32);
  }

  const unsigned short* Kg = Kb + (size_t)bh * 1024 * 64 + kq * 256 * 64;
  unsigned char* Pg = Pmat + (size_t)bh * 1024 * 1024;

  float lacc[4] = {0.f, 0.f, 0.f, 0.f};

  const int srow = t >> 3, sc8 = (t & 7) * 8;
  int4 kreg[2];
  kreg[0] = *(const int4*)(Kg + (size_t)(srow)*64 + sc8);
  kreg[1] = *(const int4*)(Kg + (size_t)(srow + 32) * 64 + sc8);
  {
    char* kb = kbuf0;
    *(int4*)(kb + swz(srow, sc8 * 2)) = kreg[0];
    *(int4*)(kb + swz(srow + 32, sc8 * 2)) = kreg[1];
  }

  for (int kc = 0; kc < 4; ++kc) {
    __syncthreads();                       // kbuf[cur] ready (one barrier/iter)
    char* kb  = (kc & 1) ? kbuf1 : kbuf0;
    char* kbn = (kc & 1) ? kbuf0 : kbuf1;
    if (kc < 3) {                          // T14: next chunk's global loads
      kreg[0] = *(const int4*)(Kg + (size_t)((kc + 1) * 64 + srow) * 64 + sc8);
      kreg[1] = *(const int4*)(Kg + (size_t)((kc + 1) * 64 + srow + 32) * 64 + sc8);
    }

    f32x4 s[4] = {};
#pragma unroll
    for (int kk = 0; kk < 2; ++kk) {
#pragma unroll
      for (int nt = 0; nt < 4; ++nt) {
        short8 bk = *(const short8*)(kb + swz(nt * 16 + lr, kk * 64 + ls * 16));
        s[nt] = mfma_bf16(qa[kk], bk, s[nt]);
      }
    }

    // p = exp2(s*c) masked; raw v_exp + branchless fp8 cvt
#pragma unroll
    for (int nt = 0; nt < 4; ++nt)
#pragma unroll
      for (int r = 0; r < 4; ++r) {
        float sv = s[nt][r];
        float pv = (sv == 0.f) ? 0.f : __builtin_amdgcn_exp2f(sv * sclog2e);
        lacc[r] += pv;
        pbuf[(ls * 4 + r) * 80 + nt * 16 + lr] = (char)f2e4m3_fast(pv);
      }

    // coalesced swizzled P write: wave tile = 16 rows x 64B
    int gkc = kq * 4 + kc;
    {
      int prow = l >> 2, pchk = l & 3;
      uchar16 pv16 = *(const uchar16*)(pbuf + prow * 80 + pchk * 16);
      int n = q0 + w * 16 + prow;
      *(uchar16*)(Pg + (size_t)n * 1024 + (gkc >> 1) * 128 +
                  (((gkc & 1) * 64 + pchk * 16) ^ ((n & 7) << 4))) = pv16;
    }

    if (kc < 3) {                          // stage next K into other buffer
      *(int4*)(kbn + swz(srow, sc8 * 2)) = kreg[0];
      *(int4*)(kbn + swz(srow + 32, sc8 * 2)) = kreg[1];
    }
  }

#pragma unroll
  for (int r = 0; r < 4; ++r) {
#pragma unroll
    for (int off = 1; off < 16; off <<= 1)
      lacc[r] += __shfl_xor(lacc[r], off, 64);
  }
  if (lr == 0) {
#pragma unroll
    for (int r = 0; r < 4; ++r)
      lsum_g[kq * 32768 + (size_t)bh * 1024 + q0 + w * 16 + ls * 4 + r] =
          lacc[r];
  }
}

// ---------------------------------------------------------------------------
// k_pv: fp8 x fp8 MFMA. BK=128 fp8 (128B rows), 4 iters, gload_lds 2-phase.
// Grid 1024 XCD-chunked: head = lid>>5, ntile = (lid>>1)&15, mhalf = lid&1.
// ---------------------------------------------------------------------------
__global__ __launch_bounds__(256) void k_pv(
    const unsigned char* __restrict__ Pmat,
    const unsigned char* __restrict__ Vt,
    const float* __restrict__ lsum_g, float* __restrict__ V1a,
    float* __restrict__ V1b) {
  __shared__ __align__(16) char Ab[2][8192];
  __shared__ __align__(16) char Bb[2][8192];
  const int id  = blockIdx.x;
  const int lid = (id & 7) * 128 + (id >> 3);
  const int head = lid >> 5;
  const int n0   = ((lid >> 1) & 15) * 64;
  const int mh   = lid & 1;
  const int t = threadIdx.x;
  const int w = t >> 6, l = t & 63, lr = l & 15, ls = l >> 4;

  const char* Pg = (const char*)(Pmat + (size_t)head * 1024 * 1024) +
                   (size_t)n0 * 1024 + mh * 512;
  const char* Vg = (const char*)(Vt + (size_t)head * 64 * 1024) + mh * 512;

  const int srow = w * 16 + (l >> 3);
  const int sc16 = (l & 7) * 16;

  f32x4 acc[4] = {};

  auto STAGE = [&](int buf, int kc) {
#pragma unroll
    for (int j = 0; j < 2; ++j) {
      int row = srow + j * 8;
      gload_lds16(Pg + (size_t)row * 1024 + kc * 128 + sc16,
                  &Ab[buf][w * 2048 + j * 1024]);
      gload_lds16(Vg + (size_t)row * 1024 + kc * 128 + sc16,
                  &Bb[buf][w * 2048 + j * 1024]);
    }
  };

  STAGE(0, 0);
  __syncthreads();
  int cur = 0;
  for (int kc = 0; kc < 4; ++kc) {
    if (kc < 3) STAGE(cur ^ 1, kc + 1);
#pragma unroll
    for (int ks = 0; ks < 4; ++ks) {
      long af = *(const long*)(&Ab[cur][swz(w * 16 + lr, ks * 32 + ls * 8)]);
#pragma unroll
      for (int nf = 0; nf < 4; ++nf) {
        long bf8 = *(const long*)(&Bb[cur][swz(nf * 16 + lr, ks * 32 + ls * 8)]);
        acc[nf] = __builtin_amdgcn_mfma_f32_16x16x32_fp8_fp8(af, bf8, acc[nf],
                                                             0, 0, 0);
      }
    }
    __syncthreads();
    cur ^= 1;
  }

  float* V1 = mh ? V1b : V1a;
  const int b = head >> 3, h = head & 7;
#pragma unroll
  for (int r = 0; r < 4; ++r) {
    int n = n0 + w * 16 + ls * 4 + r;
    size_t li = (size_t)head * 1024 + n;
    float lv = lsum_g[li] + lsum_g[32768 + li] + lsum_g[65536 + li] +
               lsum_g[98304 + li];
    float rinv = (lv > 0.f) ? 1.f / lv : 0.f;
#pragma unroll
    for (int nf = 0; nf < 4; ++nf)
      V1[((size_t)b * 1024 + n) * 512 + h * 64 + nf * 16 + lr] =
          acc[nf][r] * rinv;
  }
}

// ---------------------------------------------------------------------------
// Fused LayerNorm (+ optional transpose): y = LN(V1a+V1b+Vf).
// R12: grid 1024, 4 rows/block, one WAVE per row (wave-local reduce).
// mode 0: bf16 Vt (fallback). mode 1: fp8 Vt. mode 2: no Vt (final layer).
// ---------------------------------------------------------------------------
__global__ __launch_bounds__(256) void k_ln_t(
    const float* __restrict__ V1a, const float* __restrict__ V1b,
    const float* __restrict__ Vf_in,
    const float* __restrict__ gamma, const float* __restrict__ beta,
    float* __restrict__ Vf_out, void* __restrict__ Vt, int mode) {
  __shared__ unsigned short tile[4 * 520];
  const int blk = blockIdx.x;          // 0..1023
  const int b  = blk >> 8;
  const int n0 = (blk & 255) * 4;
  const int t = threadIdx.x;
  const int row = t >> 6;              // 0..3, one wave per row
  const int l = t & 63;
  const int c0 = l * 8;
  const size_t base = ((size_t)b * 1024 + n0 + row) * 512 + c0;

  float x[8];
  float s = 0.f, sq = 0.f;
#pragma unroll
  for (int j = 0; j < 8; j += 4) {
    float4 a0 = *(const float4*)(V1a + base + j);
    float4 a1 = *(const float4*)(V1b + base + j);
    float4 v = *(const float4*)(Vf_in + base + j);
    float4 y = {a0.x + a1.x + v.x, a0.y + a1.y + v.y, a0.z + a1.z + v.z,
                a0.w + a1.w + v.w};
    x[j + 0] = y.x; x[j + 1] = y.y; x[j + 2] = y.z; x[j + 3] = y.w;
    s  += y.x + y.y + y.z + y.w;
    sq += y.x * y.x + y.y * y.y + y.z * y.z + y.w * y.w;
  }
#pragma unroll
  for (int off = 1; off < 64; off <<= 1) {
    s  += __shfl_xor(s, off, 64);
    sq += __shfl_xor(sq, off, 64);
  }
  float mu   = s * (1.f / 512.f);
  float var  = sq * (1.f / 512.f) - mu * mu;
  float rstd = rsqrtf(var + 1e-5f);

  unsigned short* trow = tile + row * 520 + c0;
#pragma unroll
  for (int j = 0; j < 8; j += 4) {
    float4 g = *(const float4*)(gamma + c0 + j);
    float4 bb = *(const float4*)(beta + c0 + j);
    float4 y;
    y.x = (x[j + 0] - mu) * rstd * g.x + bb.x;
    y.y = (x[j + 1] - mu) * rstd * g.y + bb.y;
    y.z = (x[j + 2] - mu) * rstd * g.z + bb.z;
    y.w = (x[j + 3] - mu) * rstd * g.w + bb.w;
    *(float4*)(Vf_out + base + j) = y;
    if (mode != 2) {
      trow[j + 0] = f2bf(y.x); trow[j + 1] = f2bf(y.y);
      trow[j + 2] = f2bf(y.z); trow[j + 3] = f2bf(y.w);
    }
  }
  if (mode == 2) return;
  __syncthreads();

#pragma unroll
  for (int it = 0; it < 2; ++it) {
    int d = t + it * 256;              // 0..511 = h*64+dh
    int h = d >> 6, dh = d & 63;
    int sw = (dh & 7) << 4;
    if (mode == 0) {
      ushort4v o;
#pragma unroll
      for (int j = 0; j < 4; ++j) o[j] = tile[j * 520 + d];
      int byte0 = n0 * 2;              // multiple of 8
      char* dst = (char*)Vt + ((size_t)((b * 8 + h) * 64 + dh)) * 2048 +
                  (byte0 & ~127) + ((byte0 & 127) ^ sw);
      *(ushort4v*)dst = o;
    } else {
      uchar4v o;
#pragma unroll
      for (int j = 0; j < 4; ++j) o[j] = f2e4m3_fast(bf2f(tile[j * 520 + d]));
      char* dst = (char*)Vt + ((size_t)((b * 8 + h) * 64 + dh)) * 1024 +
                  (n0 & ~127) + ((n0 & 127) ^ sw);
      *(uchar4v*)dst = o;
    }
  }
}

// ---------------------------------------------------------------------------
// Fallback fused flash attention (ws too small only; bf16 Vt mode 0)
// ---------------------------------------------------------------------------
__global__ __launch_bounds__(256) void k_attn(
    const unsigned short* __restrict__ Qb,
    const unsigned short* __restrict__ Kb,
    const unsigned short* __restrict__ Vt,
    float* __restrict__ V1) {
  __shared__ char lds[8192 + 8192 + 4 * 16 * 144];
  char* kbuf = lds;
  char* vbuf = lds + 8192;
  const int bh = blockIdx.y;
  const int q0 = blockIdx.x * 64;
  const int t = threadIdx.x;
  const int w = t >> 6, l = t & 63, lr = l & 15, ls = l >> 4;
  char* pbuf = lds + 16384 + w * (16 * 144);

  const float scale = 0.044194173824159216f;

  short8 qa[2];
  {
    const unsigned short* Qg =
        Qb + ((size_t)bh * 1024 + q0 + w * 16 + lr) * 64 + ls * 8;
    qa[0] = *(const short8*)(Qg);
    qa[1] = *(const short8*)(Qg + 32);
  }

  f32x4 O[4] = {};
  float mrow[4], lrow[4];
#pragma unroll
  for (int r = 0; r < 4; ++r) { mrow[r] = -INFINITY; lrow[r] = 0.f; }

  const unsigned short* Kg = Kb + (size_t)bh * 1024 * 64;
  const char* Vg = (const char*)(Vt + (size_t)bh * 64 * 1024);

  for (int kc = 0; kc < 16; ++kc) {
    {
      int row = t >> 3;
      int c8  = (t & 7) * 8;
#pragma unroll
      for (int it = 0; it < 2; ++it) {
        int rr = row + it * 32;
        int4 kv = *(const int4*)(Kg + (size_t)(kc * 64 + rr) * 64 + c8);
        *(int4*)(kbuf + swz(rr, c8 * 2)) = kv;
        int swv = (rr & 7) << 4;
        int4 vv = *(const int4*)(Vg + (size_t)rr * 2048 + kc * 128 +
                                 ((c8 * 2) ^ swv));
        *(int4*)(vbuf + swz(rr, c8 * 2)) = vv;
      }
    }
    __syncthreads();

    f32x4 s[4] = {};
#pragma unroll
    for (int kk = 0; kk < 2; ++kk) {
#pragma unroll
      for (int nt = 0; nt < 4; ++nt) {
        short8 bk = *(const short8*)(kbuf + swz(nt * 16 + lr, kk * 64 + ls * 16));
        s[nt] = mfma_bf16(qa[kk], bk, s[nt]);
      }
    }

    float p[4][4];
    float cmax[4];
#pragma unroll
    for (int r = 0; r < 4; ++r) cmax[r] = -INFINITY;
#pragma unroll
    for (int nt = 0; nt < 4; ++nt)
#pragma unroll
      for (int r = 0; r < 4; ++r) {
        float sv = s[nt][r];
        p[nt][r] = (sv == 0.f) ? -INFINITY : sv * scale;
        cmax[r] = fmaxf(cmax[r], p[nt][r]);
      }
#pragma unroll
    for (int r = 0; r < 4; ++r)
#pragma unroll
      for (int off = 1; off < 16; off <<= 1)
        cmax[r] = fmaxf(cmax[r], __shfl_xor(cmax[r], off, 64));

    float alpha[4];
#pragma unroll
    for (int r = 0; r < 4; ++r) {
      float mnew = fmaxf(mrow[r], cmax[r]);
      alpha[r] = (mnew == -INFINITY) ? 1.f : exp2f((mrow[r] - mnew) * LOG2E);
      mrow[r] = mnew;
    }
    float lsum[4] = {0.f, 0.f, 0.f, 0.f};
#pragma unroll
    for (int nt = 0; nt < 4; ++nt)
#pragma unroll
      for (int r = 0; r < 4; ++r) {
        float pv = (p[nt][r] == -INFINITY)
                       ? 0.f
                       : exp2f((p[nt][r] - mrow[r]) * LOG2E);
        p[nt][r] = pv;
        lsum[r] += pv;
      }
#pragma unroll
    for (int r = 0; r < 4; ++r) {
#pragma unroll
      for (int off = 1; off < 16; off <<= 1)
        lsum[r] += __shfl_xor(lsum[r], off, 64);
      lrow[r] = lrow[r] * alpha[r] + lsum[r];
    }
#pragma unroll
    for (int dt = 0; dt < 4; ++dt)
#pragma unroll
      for (int r = 0; r < 4; ++r) O[dt][r] *= alpha[r];

#pragma unroll
    for (int nt = 0; nt < 4; ++nt)
#pragma unroll
      for (int r = 0; r < 4; ++r)
        *(unsigned short*)(pbuf + (ls * 4 + r) * 144 + (nt * 16 + lr) * 2) =
            f2bf(p[nt][r]);

#pragma unroll
    for (int kk = 0; kk < 2; ++kk) {
      short8 pa = *(const short8*)(pbuf + lr * 144 + kk * 64 + ls * 16);
#pragma unroll
      for (int dt = 0; dt < 4; ++dt) {
        short8 bv = *(const short8*)(vbuf + swz(dt * 16 + lr, kk * 64 + ls * 16));
        O[dt] = mfma_bf16(pa, bv, O[dt]);
      }
    }
    __syncthreads();
  }

  float rinv[4];
#pragma unroll
  for (int r = 0; r < 4; ++r) rinv[r] = (lrow[r] > 0.f) ? 1.f / lrow[r] : 0.f;
  const int b = bh >> 3, h = bh & 7;
#pragma unroll
  for (int dt = 0; dt < 4; ++dt)
#pragma unroll
    for (int r = 0; r < 4; ++r) {
      int n = q0 + w * 16 + ls * 4 + r;
      int c = h * 64 + dt * 16 + lr;
      V1[((size_t)b * 1024 + n) * 512 + c] = O[dt][r] * rinv[r];
    }
}

// ---------------------------------------------------------------------------
extern "C" void kernel_launch(void* const* d_in, const int* in_sizes, int n_in,
                              void* d_out, int out_size, void* d_ws,
                              size_t ws_size, hipStream_t stream) {
  const float* x1    = (const float*)d_in[0];
  const float* x2    = (const float*)d_in[1];
  const float* Wq    = (const float*)d_in[2];
  const float* Wk    = (const float*)d_in[3];
  const float* Wv    = (const float*)d_in[4];
  const float* gamma = (const float*)d_in[5];
  const float* beta  = (const float*)d_in[6];
  float* out = (float*)d_out;
  char* ws = (char*)d_ws;

  const size_t MB = 1u << 20;
  unsigned short* xb  = (unsigned short*)(ws);                 // 8 MB (dead after proj)
  unsigned short* Wqb = (unsigned short*)(ws + 8 * MB);
  unsigned short* Wkb = (unsigned short*)(ws + 8 * MB + 512 * 1024);
  unsigned short* Wvb = (unsigned short*)(ws + 9 * MB);
  unsigned short* Qb  = (unsigned short*)(ws + 10 * MB);       // 4 MB
  unsigned short* Kb  = (unsigned short*)(ws + 14 * MB);       // 4 MB
  void*           Vt  = (void*)(ws + 18 * MB);                 // 4 MB (bf16) / 2 MB (fp8)
  float*          Vf  = (float*)(ws + 22 * MB);                // 8 MB
  float*          V1a = (float*)(ws + 30 * MB);                // 8 MB
  float*          lsm = (float*)(ws + 38 * MB);                // 512 KB
  unsigned char*  Pm  = (unsigned char*)(ws + 39 * MB);        // 32 MB (fp8)
  float*          V1b = (float*)(ws);                          // reuse xb region

  const bool bigws = ws_size >= (size_t)71 * MB;

  k_convert_all<<<2560, 256, 0, stream>>>(x1, x2, Wq, Wk, Wv, xb, Wqb, Wkb,
                                          Wvb);
  k_proj<<<384, 256, 0, stream>>>(xb, Wqb, Wkb, Wvb, Qb, Kb, Vf);

  if (bigws) {
    k_transpose_v<<<dim3(16, 32), 256, 0, stream>>>(Vf, Vt, 1);
    k_scores<<<2048, 256, 0, stream>>>(Qb, Kb, Pm, lsm);
    for (int layer = 0; layer < 3; ++layer) {
      k_pv<<<1024, 256, 0, stream>>>(Pm, (const unsigned char*)Vt, lsm, V1a,
                                     V1b);
      if (layer < 2)
        k_ln_t<<<1024, 256, 0, stream>>>(V1a, V1b, Vf, gamma, beta, Vf, Vt, 1);
      else
        k_ln_t<<<1024, 256, 0, stream>>>(V1a, V1b, Vf, gamma, beta, out, Vt, 2);
    }
  } else {
    hipMemsetAsync(V1b, 0, 8 * MB, stream);
    k_transpose_v<<<dim3(16, 32), 256, 0, stream>>>(Vf, Vt, 0);
    for (int layer = 0; layer < 3; ++layer) {
      k_attn<<<dim3(16, 32), 256, 0, stream>>>(Qb, Kb,
                                               (const unsigned short*)Vt, V1a);
      if (layer < 2)
        k_ln_t<<<1024, 256, 0, stream>>>(V1a, V1b, Vf, gamma, beta, Vf, Vt, 0);
      else
        k_ln_t<<<1024, 256, 0, stream>>>(V1a, V1b, Vf, gamma, beta, out, Vt, 2);
    }
  }
}

// Round 14
// 118.424 us; speedup vs baseline: 1.2445x; 1.0627x over previous
//
#include <hip/hip_runtime.h>

// ---------------------------------------------------------------------------
// CrossModeAttention: B=4, N=1024, D1=D2=512, C=512, H=8, DH=64, LAYERS=3
// Q,K layer-invariant => P = exp(QK^T*scale) computed ONCE, fp8 e4m3 storage.
// R13: (A) V-transpose fused into k_proj epilogue (drops k_transpose_v +
// Vf re-read); (B) V1 partials stored bf16 (halves pv-write / ln-read).
// ---------------------------------------------------------------------------

#define LOG2E 1.44269504088896f

using f32x4   = __attribute__((ext_vector_type(4))) float;
using short8  = __attribute__((ext_vector_type(8))) short;
using ushort8 = __attribute__((ext_vector_type(8))) unsigned short;
using ushort4v= __attribute__((ext_vector_type(4))) unsigned short;
using uchar8  = __attribute__((ext_vector_type(8))) unsigned char;
using uchar4v = __attribute__((ext_vector_type(4))) unsigned char;
using uchar16 = __attribute__((ext_vector_type(16))) unsigned char;

__device__ inline unsigned short f2bf(float f) {
  unsigned u = __builtin_bit_cast(unsigned, f);
  u += 0x7fffu + ((u >> 16) & 1u);   // RNE
  return (unsigned short)(u >> 16);
}
__device__ inline float bf2f(unsigned short h) {
  unsigned u = (unsigned)h << 16;
  return __builtin_bit_cast(float, u);
}

// f32 -> OCP e4m3fn, branchless (~7 VALU); |f|<2^-6 flushed to 0; clamp 448.
__device__ inline unsigned char f2e4m3_fast(float f) {
  unsigned u = __builtin_bit_cast(unsigned, f);
  unsigned sign = (u >> 24) & 0x80u;
  unsigned a = u & 0x7fffffffu;
  unsigned v = a + (0x7ffffu + ((a >> 20) & 1u));   // RNE
  unsigned m = (v >> 20) - 960u;                    // (E<<3)|M
  m = (m > 126u) ? 126u : m;                        // clamp at 448
  m = (a < 0x3c000000u) ? 0u : m;                   // flush tiny/zero
  return (unsigned char)(sign | m);
}

__device__ inline f32x4 mfma_bf16(short8 a, short8 b, f32x4 c) {
  return __builtin_amdgcn_mfma_f32_16x16x32_bf16(a, b, c, 0, 0, 0);
}

__device__ inline void gload_lds16(const void* g, void* l) {
  __builtin_amdgcn_global_load_lds(
      (const __attribute__((address_space(1))) unsigned int*)g,
      (__attribute__((address_space(3))) unsigned int*)l, 16, 0, 0);
}

// XOR swizzle for 128B-row LDS tiles (G4)
__device__ inline int swz(int row, int byte_in_row) {
  return row * 128 + (byte_in_row ^ ((row & 7) << 4));
}

// ---------------------------------------------------------------------------
// Merged convert: xb bf16 [4096][1024] from x1|x2, then Wq,Wk,Wv -> bf16.
// ---------------------------------------------------------------------------
__global__ __launch_bounds__(256) void k_convert_all(
    const float* __restrict__ x1, const float* __restrict__ x2,
    const float* __restrict__ Wq, const float* __restrict__ Wk,
    const float* __restrict__ Wv,
    unsigned short* __restrict__ xb, unsigned short* __restrict__ Wqb,
    unsigned short* __restrict__ Wkb, unsigned short* __restrict__ Wvb) {
  int i = blockIdx.x * 256 + threadIdx.x;
  const float* src;
  unsigned short* dst;
  if (i < 524288) {
    int e0 = i * 8, m = e0 >> 10, d = e0 & 1023;
    src = (d < 512) ? (x1 + (size_t)m * 512 + d)
                    : (x2 + (size_t)m * 512 + (d - 512));
    dst = xb + (size_t)e0;
  } else if (i < 557056) {
    int j = (i - 524288) * 8;
    src = Wq + j; dst = Wqb + j;
  } else if (i < 589824) {
    int j = (i - 557056) * 8;
    src = Wk + j; dst = Wkb + j;
  } else {
    int j = (i - 589824) * 8;
    src = Wv + j; dst = Wvb + j;
  }
  float4 a = ((const float4*)src)[0];
  float4 b = ((const float4*)src)[1];
  ushort8 o;
  o[0] = f2bf(a.x); o[1] = f2bf(a.y); o[2] = f2bf(a.z); o[3] = f2bf(a.w);
  o[4] = f2bf(b.x); o[5] = f2bf(b.y); o[6] = f2bf(b.z); o[7] = f2bf(b.w);
  *(ushort8*)dst = o;
}

// ---------------------------------------------------------------------------
// Projections: 128x128 tile, BK=64, global_load_lds. z=0 Q, z=1 K, z=2 V.
// R13: z==2 epilogue also scatters V transposed as fp8 into Vt (writeVt=1),
// replacing the separate transpose kernel.
// ---------------------------------------------------------------------------
__global__ __launch_bounds__(256) void k_proj(
    const unsigned short* __restrict__ xb,
    const unsigned short* __restrict__ Wqb,
    const unsigned short* __restrict__ Wkb,
    const unsigned short* __restrict__ Wvb,
    unsigned short* __restrict__ Qb, unsigned short* __restrict__ Kb,
    float* __restrict__ Vf, unsigned char* __restrict__ VtF8, int writeVt) {
  __shared__ __align__(16) unsigned short Atile[128 * 64];
  __shared__ __align__(16) unsigned short Btile[128 * 64];

  const int id  = blockIdx.x;
  const int z   = id % 3;
  const int rem = id / 3;
  const int c0  = (rem & 3) * 128;
  const int m0  = (rem >> 2) * 128;

  const int K    = (z == 2) ? 1024 : 512;
  const int aoff = (z == 1) ? 512 : 0;
  const unsigned short* W = (z == 0) ? Wqb : (z == 1) ? Wkb : Wvb;

  const int t  = threadIdx.x;
  const int w  = t >> 6, l = t & 63;
  const int lr = l & 15, ls = l >> 4;
  const int wr = w >> 1, wc = w & 1;

  const int srow  = l >> 3;
  const int scol8 = (l & 7) * 8;

  f32x4 acc[4][4] = {};

  for (int k0 = 0; k0 < K; k0 += 64) {
#pragma unroll
    for (int j = 0; j < 4; ++j) {
      int ch  = w * 4 + j;
      int row = ch * 8 + srow;
      gload_lds16(xb + (size_t)(m0 + row) * 1024 + aoff + k0 + scol8,
                  Atile + ch * 512);
      gload_lds16(W + (size_t)(c0 + row) * K + k0 + scol8,
                  Btile + ch * 512);
    }
    __syncthreads();
#pragma unroll
    for (int ks = 0; ks < 2; ++ks) {
      short8 af[4], bf[4];
#pragma unroll
      for (int mf = 0; mf < 4; ++mf)
        af[mf] = *(const short8*)(Atile + (wr * 64 + mf * 16 + lr) * 64 +
                                  ks * 32 + ls * 8);
#pragma unroll
      for (int nf = 0; nf < 4; ++nf)
        bf[nf] = *(const short8*)(Btile + (wc * 64 + nf * 16 + lr) * 64 +
                                  ks * 32 + ls * 8);
#pragma unroll
      for (int mf = 0; mf < 4; ++mf)
#pragma unroll
        for (int nf = 0; nf < 4; ++nf)
          acc[mf][nf] = mfma_bf16(af[mf], bf[nf], acc[mf][nf]);
    }
    __syncthreads();
  }

#pragma unroll
  for (int mf = 0; mf < 4; ++mf)
#pragma unroll
    for (int nf = 0; nf < 4; ++nf) {
      int m = m0 + wr * 64 + mf * 16 + ls * 4;   // 4-run start (r fastest)
      int c = c0 + wc * 64 + nf * 16 + lr;
      if (z == 2) {
#pragma unroll
        for (int r = 0; r < 4; ++r)
          Vf[(size_t)(m + r) * 512 + c] = acc[mf][nf][r];
        if (writeVt) {
          int b = m >> 10, n = m & 1023, h = c >> 6, dh = c & 63;
          uchar4v o;
#pragma unroll
          for (int r = 0; r < 4; ++r) o[r] = f2e4m3_fast(acc[mf][nf][r]);
          char* dst = (char*)VtF8 +
                      ((size_t)((b * 8 + h) * 64 + dh)) * 1024 + (n & ~127) +
                      ((n & 127) ^ ((dh & 7) << 4));
          *(uchar4v*)dst = o;
        }
      } else {
#pragma unroll
        for (int r = 0; r < 4; ++r) {
          int mm = m + r;
          int b = mm >> 10, n = mm & 1023, h = c >> 6, dh = c & 63;
          size_t idx = ((size_t)(b * 8 + h) * 1024 + n) * 64 + dh;
          (z == 0 ? Qb : Kb)[idx] = f2bf(acc[mf][nf][r]);
        }
      }
    }
}

// ---------------------------------------------------------------------------
// Transpose (fallback path only): Vf f32 -> Vt bf16 [B,H,64,N], swizzled.
// ---------------------------------------------------------------------------
__global__ __launch_bounds__(256) void k_transpose_v(
    const float* __restrict__ Vf, void* __restrict__ Vt) {
  __shared__ unsigned short tile[64 * 66];
  const int bh = blockIdx.y;
  const int b = bh >> 3, h = bh & 7;
  const int n0 = blockIdx.x * 64;
  const int t = threadIdx.x;
  {
    int n = t >> 2, dh0 = (t & 3) * 16;
    const float* src = Vf + ((size_t)b * 1024 + n0 + n) * 512 + h * 64 + dh0;
    unsigned short* dst = tile + n * 66 + dh0;
#pragma unroll
    for (int j = 0; j < 16; j += 4) {
      float4 v = *(const float4*)(src + j);
      dst[j + 0] = f2bf(v.x); dst[j + 1] = f2bf(v.y);
      dst[j + 2] = f2bf(v.z); dst[j + 3] = f2bf(v.w);
    }
  }
  __syncthreads();
#pragma unroll
  for (int it = 0; it < 2; ++it) {
    int dh = (t >> 3) + it * 32, n8 = (t & 7) * 8;
    ushort8 o;
#pragma unroll
    for (int j = 0; j < 8; ++j) o[j] = tile[(n8 + j) * 66 + dh];
    char* dst = (char*)Vt + ((size_t)(bh * 64 + dh)) * 2048 + n0 * 2 +
                ((n8 * 2) ^ ((dh & 7) << 4));
    *(ushort8*)dst = o;
  }
}

// ---------------------------------------------------------------------------
// k_scores: P = exp(QK^T*scale) -> FP8 e4m3, masked (s==0 -> 0).
// Grid 2048 XCD-chunked (head = lid>>6, qtile = (lid>>2)&15, kq = lid&3);
// kbuf double-buffered -> one barrier per kc.
// ---------------------------------------------------------------------------
__global__ __launch_bounds__(256) void k_scores(
    const unsigned short* __restrict__ Qb,
    const unsigned short* __restrict__ Kb,
    unsigned char* __restrict__ Pmat, float* __restrict__ lsum_g) {
  __shared__ char lds[2 * 8192 + 4 * 16 * 80];
  char* kbuf0 = lds;
  char* kbuf1 = lds + 8192;
  const int id  = blockIdx.x;
  const int lid = (id & 7) * 256 + (id >> 3);
  const int bh  = lid >> 6;
  const int q0  = ((lid >> 2) & 15) * 64;
  const int kq  = lid & 3;
  const int t = threadIdx.x;
  const int w = t >> 6, l = t & 63, lr = l & 15, ls = l >> 4;
  char* pbuf = lds + 16384 + w * (16 * 80);

  const float sclog2e = 0.0637587160f;   // (512^-0.5) * log2(e)

  short8 qa[2];
  {
    const unsigned short* Qg =
        Qb + ((size_t)bh * 1024 + q0 + w * 16 + lr) * 64 + ls * 8;
    qa[0] = *(const short8*)(Qg);
    qa[1] = *(const short8*)(Qg + 32);
  }

  const unsigned short* Kg = Kb + (size_t)bh * 1024 * 64 + kq * 256 * 64;
  unsigned char* Pg = Pmat + (size_t)bh * 1024 * 1024;

  float lacc[4] = {0.f, 0.f, 0.f, 0.f};

  const int srow = t >> 3, sc8 = (t & 7) * 8;
  int4 kreg[2];
  kreg[0] = *(const int4*)(Kg + (size_t)(srow)*64 + sc8);
  kreg[1] = *(const int4*)(Kg + (size_t)(srow + 32) * 64 + sc8);
  {
    char* kb = kbuf0;
    *(int4*)(kb + swz(srow, sc8 * 2)) = kreg[0];
    *(int4*)(kb + swz(srow + 32, sc8 * 2)) = kreg[1];
  }

  for (int kc = 0; kc < 4; ++kc) {
    __syncthreads();
    char* kb  = (kc & 1) ? kbuf1 : kbuf0;
    char* kbn = (kc & 1) ? kbuf0 : kbuf1;
    if (kc < 3) {
      kreg[0] = *(const int4*)(Kg + (size_t)((kc + 1) * 64 + srow) * 64 + sc8);
      kreg[1] = *(const int4*)(Kg + (size_t)((kc + 1) * 64 + srow + 32) * 64 + sc8);
    }

    f32x4 s[4] = {};
#pragma unroll
    for (int kk = 0; kk < 2; ++kk) {
#pragma unroll
      for (int nt = 0; nt < 4; ++nt) {
        short8 bk = *(const short8*)(kb + swz(nt * 16 + lr, kk * 64 + ls * 16));
        s[nt] = mfma_bf16(qa[kk], bk, s[nt]);
      }
    }

#pragma unroll
    for (int nt = 0; nt < 4; ++nt)
#pragma unroll
      for (int r = 0; r < 4; ++r) {
        float sv = s[nt][r];
        float pv = (sv == 0.f) ? 0.f : __builtin_amdgcn_exp2f(sv * sclog2e);
        lacc[r] += pv;
        pbuf[(ls * 4 + r) * 80 + nt * 16 + lr] = (char)f2e4m3_fast(pv);
      }

    int gkc = kq * 4 + kc;
    {
      int prow = l >> 2, pchk = l & 3;
      uchar16 pv16 = *(const uchar16*)(pbuf + prow * 80 + pchk * 16);
      int n = q0 + w * 16 + prow;
      *(uchar16*)(Pg + (size_t)n * 1024 + (gkc >> 1) * 128 +
                  (((gkc & 1) * 64 + pchk * 16) ^ ((n & 7) << 4))) = pv16;
    }

    if (kc < 3) {
      *(int4*)(kbn + swz(srow, sc8 * 2)) = kreg[0];
      *(int4*)(kbn + swz(srow + 32, sc8 * 2)) = kreg[1];
    }
  }

#pragma unroll
  for (int r = 0; r < 4; ++r) {
#pragma unroll
    for (int off = 1; off < 16; off <<= 1)
      lacc[r] += __shfl_xor(lacc[r], off, 64);
  }
  if (lr == 0) {
#pragma unroll
    for (int r = 0; r < 4; ++r)
      lsum_g[kq * 32768 + (size_t)bh * 1024 + q0 + w * 16 + ls * 4 + r] =
          lacc[r];
  }
}

// ---------------------------------------------------------------------------
// k_pv: fp8 x fp8 MFMA. BK=128 fp8, 4 iters, gload_lds 2-phase dbuf.
// Grid 1024 XCD-chunked. R13: V1 partials written bf16.
// ---------------------------------------------------------------------------
__global__ __launch_bounds__(256) void k_pv(
    const unsigned char* __restrict__ Pmat,
    const unsigned char* __restrict__ Vt,
    const float* __restrict__ lsum_g, unsigned short* __restrict__ V1a,
    unsigned short* __restrict__ V1b) {
  __shared__ __align__(16) char Ab[2][8192];
  __shared__ __align__(16) char Bb[2][8192];
  const int id  = blockIdx.x;
  const int lid = (id & 7) * 128 + (id >> 3);
  const int head = lid >> 5;
  const int n0   = ((lid >> 1) & 15) * 64;
  const int mh   = lid & 1;
  const int t = threadIdx.x;
  const int w = t >> 6, l = t & 63, lr = l & 15, ls = l >> 4;

  const char* Pg = (const char*)(Pmat + (size_t)head * 1024 * 1024) +
                   (size_t)n0 * 1024 + mh * 512;
  const char* Vg = (const char*)(Vt + (size_t)head * 64 * 1024) + mh * 512;

  const int srow = w * 16 + (l >> 3);
  const int sc16 = (l & 7) * 16;

  f32x4 acc[4] = {};

  auto STAGE = [&](int buf, int kc) {
#pragma unroll
    for (int j = 0; j < 2; ++j) {
      int row = srow + j * 8;
      gload_lds16(Pg + (size_t)row * 1024 + kc * 128 + sc16,
                  &Ab[buf][w * 2048 + j * 1024]);
      gload_lds16(Vg + (size_t)row * 1024 + kc * 128 + sc16,
                  &Bb[buf][w * 2048 + j * 1024]);
    }
  };

  STAGE(0, 0);
  __syncthreads();
  int cur = 0;
  for (int kc = 0; kc < 4; ++kc) {
    if (kc < 3) STAGE(cur ^ 1, kc + 1);
#pragma unroll
    for (int ks = 0; ks < 4; ++ks) {
      long af = *(const long*)(&Ab[cur][swz(w * 16 + lr, ks * 32 + ls * 8)]);
#pragma unroll
      for (int nf = 0; nf < 4; ++nf) {
        long bf8 = *(const long*)(&Bb[cur][swz(nf * 16 + lr, ks * 32 + ls * 8)]);
        acc[nf] = __builtin_amdgcn_mfma_f32_16x16x32_fp8_fp8(af, bf8, acc[nf],
                                                             0, 0, 0);
      }
    }
    __syncthreads();
    cur ^= 1;
  }

  unsigned short* V1 = mh ? V1b : V1a;
  const int b = head >> 3, h = head & 7;
#pragma unroll
  for (int r = 0; r < 4; ++r) {
    int n = n0 + w * 16 + ls * 4 + r;
    size_t li = (size_t)head * 1024 + n;
    float lv = lsum_g[li] + lsum_g[32768 + li] + lsum_g[65536 + li] +
               lsum_g[98304 + li];
    float rinv = (lv > 0.f) ? 1.f / lv : 0.f;
#pragma unroll
    for (int nf = 0; nf < 4; ++nf)
      V1[((size_t)b * 1024 + n) * 512 + h * 64 + nf * 16 + lr] =
          f2bf(acc[nf][r] * rinv);
  }
}

// ---------------------------------------------------------------------------
// Fused LayerNorm (+ optional transpose): y = LN(V1a+V1b+Vf).
// Grid 1024, 4 rows/block, one wave per row. V1 partials bf16 (R13).
// mode 0: bf16 Vt (fallback). mode 1: fp8 Vt. mode 2: no Vt (final layer).
// ---------------------------------------------------------------------------
__global__ __launch_bounds__(256) void k_ln_t(
    const unsigned short* __restrict__ V1a,
    const unsigned short* __restrict__ V1b,
    const float* __restrict__ Vf_in,
    const float* __restrict__ gamma, const float* __restrict__ beta,
    float* __restrict__ Vf_out, void* __restrict__ Vt, int mode) {
  __shared__ unsigned short tile[4 * 520];
  const int blk = blockIdx.x;          // 0..1023
  const int b  = blk >> 8;
  const int n0 = (blk & 255) * 4;
  const int t = threadIdx.x;
  const int row = t >> 6;              // 0..3, one wave per row
  const int l = t & 63;
  const int c0 = l * 8;
  const size_t base = ((size_t)b * 1024 + n0 + row) * 512 + c0;

  float x[8];
  float s = 0.f, sq = 0.f;
  {
    ushort8 a0 = *(const ushort8*)(V1a + base);
    ushort8 a1 = *(const ushort8*)(V1b + base);
    float4 v0 = *(const float4*)(Vf_in + base);
    float4 v1 = *(const float4*)(Vf_in + base + 4);
#pragma unroll
    for (int j = 0; j < 8; ++j) {
      float vf = (j < 4) ? ((const float*)&v0)[j] : ((const float*)&v1)[j - 4];
      float y = bf2f(a0[j]) + bf2f(a1[j]) + vf;
      x[j] = y;
      s += y;
      sq += y * y;
    }
  }
#pragma unroll
  for (int off = 1; off < 64; off <<= 1) {
    s  += __shfl_xor(s, off, 64);
    sq += __shfl_xor(sq, off, 64);
  }
  float mu   = s * (1.f / 512.f);
  float var  = sq * (1.f / 512.f) - mu * mu;
  float rstd = rsqrtf(var + 1e-5f);

  unsigned short* trow = tile + row * 520 + c0;
#pragma unroll
  for (int j = 0; j < 8; j += 4) {
    float4 g = *(const float4*)(gamma + c0 + j);
    float4 bb = *(const float4*)(beta + c0 + j);
    float4 y;
    y.x = (x[j + 0] - mu) * rstd * g.x + bb.x;
    y.y = (x[j + 1] - mu) * rstd * g.y + bb.y;
    y.z = (x[j + 2] - mu) * rstd * g.z + bb.z;
    y.w = (x[j + 3] - mu) * rstd * g.w + bb.w;
    *(float4*)(Vf_out + base + j) = y;
    if (mode != 2) {
      trow[j + 0] = f2bf(y.x); trow[j + 1] = f2bf(y.y);
      trow[j + 2] = f2bf(y.z); trow[j + 3] = f2bf(y.w);
    }
  }
  if (mode == 2) return;
  __syncthreads();

#pragma unroll
  for (int it = 0; it < 2; ++it) {
    int d = t + it * 256;              // 0..511 = h*64+dh
    int h = d >> 6, dh = d & 63;
    int sw = (dh & 7) << 4;
    if (mode == 0) {
      ushort4v o;
#pragma unroll
      for (int j = 0; j < 4; ++j) o[j] = tile[j * 520 + d];
      int byte0 = n0 * 2;
      char* dst = (char*)Vt + ((size_t)((b * 8 + h) * 64 + dh)) * 2048 +
                  (byte0 & ~127) + ((byte0 & 127) ^ sw);
      *(ushort4v*)dst = o;
    } else {
      uchar4v o;
#pragma unroll
      for (int j = 0; j < 4; ++j) o[j] = f2e4m3_fast(bf2f(tile[j * 520 + d]));
      char* dst = (char*)Vt + ((size_t)((b * 8 + h) * 64 + dh)) * 1024 +
                  (n0 & ~127) + ((n0 & 127) ^ sw);
      *(uchar4v*)dst = o;
    }
  }
}

// ---------------------------------------------------------------------------
// Fallback fused flash attention (ws too small only; bf16 Vt, bf16 V1 out)
// ---------------------------------------------------------------------------
__global__ __launch_bounds__(256) void k_attn(
    const unsigned short* __restrict__ Qb,
    const unsigned short* __restrict__ Kb,
    const unsigned short* __restrict__ Vt,
    unsigned short* __restrict__ V1) {
  __shared__ char lds[8192 + 8192 + 4 * 16 * 144];
  char* kbuf = lds;
  char* vbuf = lds + 8192;
  const int bh = blockIdx.y;
  const int q0 = blockIdx.x * 64;
  const int t = threadIdx.x;
  const int w = t >> 6, l = t & 63, lr = l & 15, ls = l >> 4;
  char* pbuf = lds + 16384 + w * (16 * 144);

  const float scale = 0.044194173824159216f;

  short8 qa[2];
  {
    const unsigned short* Qg =
        Qb + ((size_t)bh * 1024 + q0 + w * 16 + lr) * 64 + ls * 8;
    qa[0] = *(const short8*)(Qg);
    qa[1] = *(const short8*)(Qg + 32);
  }

  f32x4 O[4] = {};
  float mrow[4], lrow[4];
#pragma unroll
  for (int r = 0; r < 4; ++r) { mrow[r] = -INFINITY; lrow[r] = 0.f; }

  const unsigned short* Kg = Kb + (size_t)bh * 1024 * 64;
  const char* Vg = (const char*)(Vt + (size_t)bh * 64 * 1024);

  for (int kc = 0; kc < 16; ++kc) {
    {
      int row = t >> 3;
      int c8  = (t & 7) * 8;
#pragma unroll
      for (int it = 0; it < 2; ++it) {
        int rr = row + it * 32;
        int4 kv = *(const int4*)(Kg + (size_t)(kc * 64 + rr) * 64 + c8);
        *(int4*)(kbuf + swz(rr, c8 * 2)) = kv;
        int swv = (rr & 7) << 4;
        int4 vv = *(const int4*)(Vg + (size_t)rr * 2048 + kc * 128 +
                                 ((c8 * 2) ^ swv));
        *(int4*)(vbuf + swz(rr, c8 * 2)) = vv;
      }
    }
    __syncthreads();

    f32x4 s[4] = {};
#pragma unroll
    for (int kk = 0; kk < 2; ++kk) {
#pragma unroll
      for (int nt = 0; nt < 4; ++nt) {
        short8 bk = *(const short8*)(kbuf + swz(nt * 16 + lr, kk * 64 + ls * 16));
        s[nt] = mfma_bf16(qa[kk], bk, s[nt]);
      }
    }

    float p[4][4];
    float cmax[4];
#pragma unroll
    for (int r = 0; r < 4; ++r) cmax[r] = -INFINITY;
#pragma unroll
    for (int nt = 0; nt < 4; ++nt)
#pragma unroll
      for (int r = 0; r < 4; ++r) {
        float sv = s[nt][r];
        p[nt][r] = (sv == 0.f) ? -INFINITY : sv * scale;
        cmax[r] = fmaxf(cmax[r], p[nt][r]);
      }
#pragma unroll
    for (int r = 0; r < 4; ++r)
#pragma unroll
      for (int off = 1; off < 16; off <<= 1)
        cmax[r] = fmaxf(cmax[r], __shfl_xor(cmax[r], off, 64));

    float alpha[4];
#pragma unroll
    for (int r = 0; r < 4; ++r) {
      float mnew = fmaxf(mrow[r], cmax[r]);
      alpha[r] = (mnew == -INFINITY) ? 1.f : exp2f((mrow[r] - mnew) * LOG2E);
      mrow[r] = mnew;
    }
    float lsum[4] = {0.f, 0.f, 0.f, 0.f};
#pragma unroll
    for (int nt = 0; nt < 4; ++nt)
#pragma unroll
      for (int r = 0; r < 4; ++r) {
        float pv = (p[nt][r] == -INFINITY)
                       ? 0.f
                       : exp2f((p[nt][r] - mrow[r]) * LOG2E);
        p[nt][r] = pv;
        lsum[r] += pv;
      }
#pragma unroll
    for (int r = 0; r < 4; ++r) {
#pragma unroll
      for (int off = 1; off < 16; off <<= 1)
        lsum[r] += __shfl_xor(lsum[r], off, 64);
      lrow[r] = lrow[r] * alpha[r] + lsum[r];
    }
#pragma unroll
    for (int dt = 0; dt < 4; ++dt)
#pragma unroll
      for (int r = 0; r < 4; ++r) O[dt][r] *= alpha[r];

#pragma unroll
    for (int nt = 0; nt < 4; ++nt)
#pragma unroll
      for (int r = 0; r < 4; ++r)
        *(unsigned short*)(pbuf + (ls * 4 + r) * 144 + (nt * 16 + lr) * 2) =
            f2bf(p[nt][r]);

#pragma unroll
    for (int kk = 0; kk < 2; ++kk) {
      short8 pa = *(const short8*)(pbuf + lr * 144 + kk * 64 + ls * 16);
#pragma unroll
      for (int dt = 0; dt < 4; ++dt) {
        short8 bv = *(const short8*)(vbuf + swz(dt * 16 + lr, kk * 64 + ls * 16));
        O[dt] = mfma_bf16(pa, bv, O[dt]);
      }
    }
    __syncthreads();
  }

  float rinv[4];
#pragma unroll
  for (int r = 0; r < 4; ++r) rinv[r] = (lrow[r] > 0.f) ? 1.f / lrow[r] : 0.f;
  const int b = bh >> 3, h = bh & 7;
#pragma unroll
  for (int dt = 0; dt < 4; ++dt)
#pragma unroll
    for (int r = 0; r < 4; ++r) {
      int n = q0 + w * 16 + ls * 4 + r;
      int c = h * 64 + dt * 16 + lr;
      V1[((size_t)b * 1024 + n) * 512 + c] = f2bf(O[dt][r] * rinv[r]);
    }
}

// ---------------------------------------------------------------------------
extern "C" void kernel_launch(void* const* d_in, const int* in_sizes, int n_in,
                              void* d_out, int out_size, void* d_ws,
                              size_t ws_size, hipStream_t stream) {
  const float* x1    = (const float*)d_in[0];
  const float* x2    = (const float*)d_in[1];
  const float* Wq    = (const float*)d_in[2];
  const float* Wk    = (const float*)d_in[3];
  const float* Wv    = (const float*)d_in[4];
  const float* gamma = (const float*)d_in[5];
  const float* beta  = (const float*)d_in[6];
  float* out = (float*)d_out;
  char* ws = (char*)d_ws;

  const size_t MB = 1u << 20;
  unsigned short* xb  = (unsigned short*)(ws);                 // 8 MB (dead after proj)
  unsigned short* Wqb = (unsigned short*)(ws + 8 * MB);
  unsigned short* Wkb = (unsigned short*)(ws + 8 * MB + 512 * 1024);
  unsigned short* Wvb = (unsigned short*)(ws + 9 * MB);
  unsigned short* Qb  = (unsigned short*)(ws + 10 * MB);       // 4 MB
  unsigned short* Kb  = (unsigned short*)(ws + 14 * MB);       // 4 MB
  void*           Vt  = (void*)(ws + 18 * MB);                 // 4 MB bf16 / 2 MB fp8
  float*          Vf  = (float*)(ws + 22 * MB);                // 8 MB
  unsigned short* V1a = (unsigned short*)(ws + 30 * MB);       // 4 MB (bf16)
  float*          lsm = (float*)(ws + 38 * MB);                // 512 KB
  unsigned char*  Pm  = (unsigned char*)(ws + 39 * MB);        // 32 MB (fp8)
  unsigned short* V1b = (unsigned short*)(ws);                 // reuse xb region

  const bool bigws = ws_size >= (size_t)71 * MB;

  k_convert_all<<<2560, 256, 0, stream>>>(x1, x2, Wq, Wk, Wv, xb, Wqb, Wkb,
                                          Wvb);
  k_proj<<<384, 256, 0, stream>>>(xb, Wqb, Wkb, Wvb, Qb, Kb, Vf,
                                  (unsigned char*)Vt, bigws ? 1 : 0);

  if (bigws) {
    k_scores<<<2048, 256, 0, stream>>>(Qb, Kb, Pm, lsm);
    for (int layer = 0; layer < 3; ++layer) {
      k_pv<<<1024, 256, 0, stream>>>(Pm, (const unsigned char*)Vt, lsm, V1a,
                                     V1b);
      if (layer < 2)
        k_ln_t<<<1024, 256, 0, stream>>>(V1a, V1b, Vf, gamma, beta, Vf, Vt, 1);
      else
        k_ln_t<<<1024, 256, 0, stream>>>(V1a, V1b, Vf, gamma, beta, out, Vt, 2);
    }
  } else {
    hipMemsetAsync(V1b, 0, 4 * MB, stream);
    k_transpose_v<<<dim3(16, 32), 256, 0, stream>>>(Vf, Vt);
    for (int layer = 0; layer < 3; ++layer) {
      k_attn<<<dim3(16, 32), 256, 0, stream>>>(Qb, Kb,
                                               (const unsigned short*)Vt, V1a);
      if (layer < 2)
        k_ln_t<<<1024, 256, 0, stream>>>(V1a, V1b, Vf, gamma, beta, Vf, Vt, 0);
      else
        k_ln_t<<<1024, 256, 0, stream>>>(V1a, V1b, Vf, gamma, beta, out, Vt, 2);
    }
  }
}

// Round 15
// 111.473 us; speedup vs baseline: 1.3221x; 1.0624x over previous
//
#include <hip/hip_runtime.h>

// ---------------------------------------------------------------------------
// CrossModeAttention: B=4, N=1024, D1=D2=512, C=512, H=8, DH=64, LAYERS=3
// Q,K layer-invariant => P = exp(QK^T*scale) computed ONCE, fp8 e4m3 storage.
// R15: k_proj 64x128 tiles (grid 768, occupancy) + Vf stored bf16
// (halves residual traffic through the LN chain).
// ---------------------------------------------------------------------------

#define LOG2E 1.44269504088896f

using f32x4   = __attribute__((ext_vector_type(4))) float;
using short8  = __attribute__((ext_vector_type(8))) short;
using ushort8 = __attribute__((ext_vector_type(8))) unsigned short;
using ushort4v= __attribute__((ext_vector_type(4))) unsigned short;
using uchar8  = __attribute__((ext_vector_type(8))) unsigned char;
using uchar4v = __attribute__((ext_vector_type(4))) unsigned char;
using uchar16 = __attribute__((ext_vector_type(16))) unsigned char;

__device__ inline unsigned short f2bf(float f) {
  unsigned u = __builtin_bit_cast(unsigned, f);
  u += 0x7fffu + ((u >> 16) & 1u);   // RNE
  return (unsigned short)(u >> 16);
}
__device__ inline float bf2f(unsigned short h) {
  unsigned u = (unsigned)h << 16;
  return __builtin_bit_cast(float, u);
}

// f32 -> OCP e4m3fn, branchless (~7 VALU); |f|<2^-6 flushed to 0; clamp 448.
__device__ inline unsigned char f2e4m3_fast(float f) {
  unsigned u = __builtin_bit_cast(unsigned, f);
  unsigned sign = (u >> 24) & 0x80u;
  unsigned a = u & 0x7fffffffu;
  unsigned v = a + (0x7ffffu + ((a >> 20) & 1u));   // RNE
  unsigned m = (v >> 20) - 960u;                    // (E<<3)|M
  m = (m > 126u) ? 126u : m;                        // clamp at 448
  m = (a < 0x3c000000u) ? 0u : m;                   // flush tiny/zero
  return (unsigned char)(sign | m);
}

__device__ inline f32x4 mfma_bf16(short8 a, short8 b, f32x4 c) {
  return __builtin_amdgcn_mfma_f32_16x16x32_bf16(a, b, c, 0, 0, 0);
}

__device__ inline void gload_lds16(const void* g, void* l) {
  __builtin_amdgcn_global_load_lds(
      (const __attribute__((address_space(1))) unsigned int*)g,
      (__attribute__((address_space(3))) unsigned int*)l, 16, 0, 0);
}

// XOR swizzle for 128B-row LDS tiles (G4)
__device__ inline int swz(int row, int byte_in_row) {
  return row * 128 + (byte_in_row ^ ((row & 7) << 4));
}

// ---------------------------------------------------------------------------
// Merged convert: xb bf16 [4096][1024] from x1|x2, then Wq,Wk,Wv -> bf16.
// ---------------------------------------------------------------------------
__global__ __launch_bounds__(256) void k_convert_all(
    const float* __restrict__ x1, const float* __restrict__ x2,
    const float* __restrict__ Wq, const float* __restrict__ Wk,
    const float* __restrict__ Wv,
    unsigned short* __restrict__ xb, unsigned short* __restrict__ Wqb,
    unsigned short* __restrict__ Wkb, unsigned short* __restrict__ Wvb) {
  int i = blockIdx.x * 256 + threadIdx.x;
  const float* src;
  unsigned short* dst;
  if (i < 524288) {
    int e0 = i * 8, m = e0 >> 10, d = e0 & 1023;
    src = (d < 512) ? (x1 + (size_t)m * 512 + d)
                    : (x2 + (size_t)m * 512 + (d - 512));
    dst = xb + (size_t)e0;
  } else if (i < 557056) {
    int j = (i - 524288) * 8;
    src = Wq + j; dst = Wqb + j;
  } else if (i < 589824) {
    int j = (i - 557056) * 8;
    src = Wk + j; dst = Wkb + j;
  } else {
    int j = (i - 589824) * 8;
    src = Wv + j; dst = Wvb + j;
  }
  float4 a = ((const float4*)src)[0];
  float4 b = ((const float4*)src)[1];
  ushort8 o;
  o[0] = f2bf(a.x); o[1] = f2bf(a.y); o[2] = f2bf(a.z); o[3] = f2bf(a.w);
  o[4] = f2bf(b.x); o[5] = f2bf(b.y); o[6] = f2bf(b.z); o[7] = f2bf(b.w);
  *(ushort8*)dst = o;
}

// ---------------------------------------------------------------------------
// Projections: R15 = 64x128 tile (grid 768 = 3 z x 64 m x 4 c), BK=64,
// global_load_lds. z=0 Q, z=1 K, z=2 V. 4 waves, each 64m x 32c (acc[4][2]).
// z==2 epilogue: Vf bf16 + fp8 swizzled Vt scatter (writeVt=1).
// ---------------------------------------------------------------------------
__global__ __launch_bounds__(256) void k_proj(
    const unsigned short* __restrict__ xb,
    const unsigned short* __restrict__ Wqb,
    const unsigned short* __restrict__ Wkb,
    const unsigned short* __restrict__ Wvb,
    unsigned short* __restrict__ Qb, unsigned short* __restrict__ Kb,
    unsigned short* __restrict__ Vf, unsigned char* __restrict__ VtF8,
    int writeVt) {
  __shared__ __align__(16) unsigned short Atile[64 * 64];    // 8 KB
  __shared__ __align__(16) unsigned short Btile[128 * 64];   // 16 KB

  const int id  = blockIdx.x;
  const int z   = id % 3;
  const int rem = id / 3;             // 0..255
  const int c0  = (rem & 3) * 128;
  const int m0  = (rem >> 2) * 64;

  const int K    = (z == 2) ? 1024 : 512;
  const int aoff = (z == 1) ? 512 : 0;
  const unsigned short* W = (z == 0) ? Wqb : (z == 1) ? Wkb : Wvb;

  const int t  = threadIdx.x;
  const int w  = t >> 6, l = t & 63;
  const int lr = l & 15, ls = l >> 4;

  const int srow  = l >> 3;           // 0..7
  const int scol8 = (l & 7) * 8;

  f32x4 acc[4][2] = {};

  for (int k0 = 0; k0 < K; k0 += 64) {
#pragma unroll
    for (int j = 0; j < 2; ++j) {      // A: 8 chunks, 2 per wave
      int ch  = w * 2 + j;
      int row = ch * 8 + srow;
      gload_lds16(xb + (size_t)(m0 + row) * 1024 + aoff + k0 + scol8,
                  Atile + ch * 512);
    }
#pragma unroll
    for (int j = 0; j < 4; ++j) {      // B: 16 chunks, 4 per wave
      int ch  = w * 4 + j;
      int row = ch * 8 + srow;
      gload_lds16(W + (size_t)(c0 + row) * K + k0 + scol8,
                  Btile + ch * 512);
    }
    __syncthreads();
#pragma unroll
    for (int ks = 0; ks < 2; ++ks) {
      short8 af[4], bf[2];
#pragma unroll
      for (int mf = 0; mf < 4; ++mf)
        af[mf] = *(const short8*)(Atile + (mf * 16 + lr) * 64 + ks * 32 +
                                  ls * 8);
#pragma unroll
      for (int nf = 0; nf < 2; ++nf)
        bf[nf] = *(const short8*)(Btile + (w * 32 + nf * 16 + lr) * 64 +
                                  ks * 32 + ls * 8);
#pragma unroll
      for (int mf = 0; mf < 4; ++mf)
#pragma unroll
        for (int nf = 0; nf < 2; ++nf)
          acc[mf][nf] = mfma_bf16(af[mf], bf[nf], acc[mf][nf]);
    }
    __syncthreads();
  }

#pragma unroll
  for (int mf = 0; mf < 4; ++mf)
#pragma unroll
    for (int nf = 0; nf < 2; ++nf) {
      int m = m0 + mf * 16 + ls * 4;           // 4-run start (r fastest)
      int c = c0 + w * 32 + nf * 16 + lr;
      if (z == 2) {
#pragma unroll
        for (int r = 0; r < 4; ++r)
          Vf[(size_t)(m + r) * 512 + c] = f2bf(acc[mf][nf][r]);
        if (writeVt) {
          int b = m >> 10, n = m & 1023, h = c >> 6, dh = c & 63;
          uchar4v o;
#pragma unroll
          for (int r = 0; r < 4; ++r) o[r] = f2e4m3_fast(acc[mf][nf][r]);
          char* dst = (char*)VtF8 +
                      ((size_t)((b * 8 + h) * 64 + dh)) * 1024 + (n & ~127) +
                      ((n & 127) ^ ((dh & 7) << 4));
          *(uchar4v*)dst = o;
        }
      } else {
#pragma unroll
        for (int r = 0; r < 4; ++r) {
          int mm = m + r;
          int b = mm >> 10, n = mm & 1023, h = c >> 6, dh = c & 63;
          size_t idx = ((size_t)(b * 8 + h) * 1024 + n) * 64 + dh;
          (z == 0 ? Qb : Kb)[idx] = f2bf(acc[mf][nf][r]);
        }
      }
    }
}

// ---------------------------------------------------------------------------
// Transpose (fallback path only): Vf bf16 -> Vt bf16 [B,H,64,N], swizzled.
// ---------------------------------------------------------------------------
__global__ __launch_bounds__(256) void k_transpose_v(
    const unsigned short* __restrict__ Vf, void* __restrict__ Vt) {
  __shared__ unsigned short tile[64 * 66];
  const int bh = blockIdx.y;
  const int b = bh >> 3, h = bh & 7;
  const int n0 = blockIdx.x * 64;
  const int t = threadIdx.x;
  {
    int n = t >> 2, dh0 = (t & 3) * 16;
    const unsigned short* src =
        Vf + ((size_t)b * 1024 + n0 + n) * 512 + h * 64 + dh0;
    unsigned short* dst = tile + n * 66 + dh0;
#pragma unroll
    for (int j = 0; j < 16; j += 8) *(ushort8*)(dst + j) = *(const ushort8*)(src + j);
  }
  __syncthreads();
#pragma unroll
  for (int it = 0; it < 2; ++it) {
    int dh = (t >> 3) + it * 32, n8 = (t & 7) * 8;
    ushort8 o;
#pragma unroll
    for (int j = 0; j < 8; ++j) o[j] = tile[(n8 + j) * 66 + dh];
    char* dst = (char*)Vt + ((size_t)(bh * 64 + dh)) * 2048 + n0 * 2 +
                ((n8 * 2) ^ ((dh & 7) << 4));
    *(ushort8*)dst = o;
  }
}

// ---------------------------------------------------------------------------
// k_scores: P = exp(QK^T*scale) -> FP8 e4m3, masked (s==0 -> 0).
// Grid 2048 XCD-chunked; kbuf double-buffered -> one barrier per kc.
// ---------------------------------------------------------------------------
__global__ __launch_bounds__(256) void k_scores(
    const unsigned short* __restrict__ Qb,
    const unsigned short* __restrict__ Kb,
    unsigned char* __restrict__ Pmat, float* __restrict__ lsum_g) {
  __shared__ char lds[2 * 8192 + 4 * 16 * 80];
  char* kbuf0 = lds;
  char* kbuf1 = lds + 8192;
  const int id  = blockIdx.x;
  const int lid = (id & 7) * 256 + (id >> 3);
  const int bh  = lid >> 6;
  const int q0  = ((lid >> 2) & 15) * 64;
  const int kq  = lid & 3;
  const int t = threadIdx.x;
  const int w = t >> 6, l = t & 63, lr = l & 15, ls = l >> 4;
  char* pbuf = lds + 16384 + w * (16 * 80);

  const float sclog2e = 0.0637587160f;   // (512^-0.5) * log2(e)

  short8 qa[2];
  {
    const unsigned short* Qg =
        Qb + ((size_t)bh * 1024 + q0 + w * 16 + lr) * 64 + ls * 8;
    qa[0] = *(const short8*)(Qg);
    qa[1] = *(const short8*)(Qg + 32);
  }

  const unsigned short* Kg = Kb + (size_t)bh * 1024 * 64 + kq * 256 * 64;
  unsigned char* Pg = Pmat + (size_t)bh * 1024 * 1024;

  float lacc[4] = {0.f, 0.f, 0.f, 0.f};

  const int srow = t >> 3, sc8 = (t & 7) * 8;
  int4 kreg[2];
  kreg[0] = *(const int4*)(Kg + (size_t)(srow)*64 + sc8);
  kreg[1] = *(const int4*)(Kg + (size_t)(srow + 32) * 64 + sc8);
  {
    char* kb = kbuf0;
    *(int4*)(kb + swz(srow, sc8 * 2)) = kreg[0];
    *(int4*)(kb + swz(srow + 32, sc8 * 2)) = kreg[1];
  }

  for (int kc = 0; kc < 4; ++kc) {
    __syncthreads();
    char* kb  = (kc & 1) ? kbuf1 : kbuf0;
    char* kbn = (kc & 1) ? kbuf0 : kbuf1;
    if (kc < 3) {
      kreg[0] = *(const int4*)(Kg + (size_t)((kc + 1) * 64 + srow) * 64 + sc8);
      kreg[1] = *(const int4*)(Kg + (size_t)((kc + 1) * 64 + srow + 32) * 64 + sc8);
    }

    f32x4 s[4] = {};
#pragma unroll
    for (int kk = 0; kk < 2; ++kk) {
#pragma unroll
      for (int nt = 0; nt < 4; ++nt) {
        short8 bk = *(const short8*)(kb + swz(nt * 16 + lr, kk * 64 + ls * 16));
        s[nt] = mfma_bf16(qa[kk], bk, s[nt]);
      }
    }

#pragma unroll
    for (int nt = 0; nt < 4; ++nt)
#pragma unroll
      for (int r = 0; r < 4; ++r) {
        float sv = s[nt][r];
        float pv = (sv == 0.f) ? 0.f : __builtin_amdgcn_exp2f(sv * sclog2e);
        lacc[r] += pv;
        pbuf[(ls * 4 + r) * 80 + nt * 16 + lr] = (char)f2e4m3_fast(pv);
      }

    int gkc = kq * 4 + kc;
    {
      int prow = l >> 2, pchk = l & 3;
      uchar16 pv16 = *(const uchar16*)(pbuf + prow * 80 + pchk * 16);
      int n = q0 + w * 16 + prow;
      *(uchar16*)(Pg + (size_t)n * 1024 + (gkc >> 1) * 128 +
                  (((gkc & 1) * 64 + pchk * 16) ^ ((n & 7) << 4))) = pv16;
    }

    if (kc < 3) {
      *(int4*)(kbn + swz(srow, sc8 * 2)) = kreg[0];
      *(int4*)(kbn + swz(srow + 32, sc8 * 2)) = kreg[1];
    }
  }

#pragma unroll
  for (int r = 0; r < 4; ++r) {
#pragma unroll
    for (int off = 1; off < 16; off <<= 1)
      lacc[r] += __shfl_xor(lacc[r], off, 64);
  }
  if (lr == 0) {
#pragma unroll
    for (int r = 0; r < 4; ++r)
      lsum_g[kq * 32768 + (size_t)bh * 1024 + q0 + w * 16 + ls * 4 + r] =
          lacc[r];
  }
}

// ---------------------------------------------------------------------------
// k_pv: fp8 x fp8 MFMA. BK=128 fp8, 4 iters, gload_lds 2-phase dbuf.
// Grid 1024 XCD-chunked. V1 partials bf16.
// ---------------------------------------------------------------------------
__global__ __launch_bounds__(256) void k_pv(
    const unsigned char* __restrict__ Pmat,
    const unsigned char* __restrict__ Vt,
    const float* __restrict__ lsum_g, unsigned short* __restrict__ V1a,
    unsigned short* __restrict__ V1b) {
  __shared__ __align__(16) char Ab[2][8192];
  __shared__ __align__(16) char Bb[2][8192];
  const int id  = blockIdx.x;
  const int lid = (id & 7) * 128 + (id >> 3);
  const int head = lid >> 5;
  const int n0   = ((lid >> 1) & 15) * 64;
  const int mh   = lid & 1;
  const int t = threadIdx.x;
  const int w = t >> 6, l = t & 63, lr = l & 15, ls = l >> 4;

  const char* Pg = (const char*)(Pmat + (size_t)head * 1024 * 1024) +
                   (size_t)n0 * 1024 + mh * 512;
  const char* Vg = (const char*)(Vt + (size_t)head * 64 * 1024) + mh * 512;

  const int srow = w * 16 + (l >> 3);
  const int sc16 = (l & 7) * 16;

  f32x4 acc[4] = {};

  auto STAGE = [&](int buf, int kc) {
#pragma unroll
    for (int j = 0; j < 2; ++j) {
      int row = srow + j * 8;
      gload_lds16(Pg + (size_t)row * 1024 + kc * 128 + sc16,
                  &Ab[buf][w * 2048 + j * 1024]);
      gload_lds16(Vg + (size_t)row * 1024 + kc * 128 + sc16,
                  &Bb[buf][w * 2048 + j * 1024]);
    }
  };

  STAGE(0, 0);
  __syncthreads();
  int cur = 0;
  for (int kc = 0; kc < 4; ++kc) {
    if (kc < 3) STAGE(cur ^ 1, kc + 1);
#pragma unroll
    for (int ks = 0; ks < 4; ++ks) {
      long af = *(const long*)(&Ab[cur][swz(w * 16 + lr, ks * 32 + ls * 8)]);
#pragma unroll
      for (int nf = 0; nf < 4; ++nf) {
        long bf8 = *(const long*)(&Bb[cur][swz(nf * 16 + lr, ks * 32 + ls * 8)]);
        acc[nf] = __builtin_amdgcn_mfma_f32_16x16x32_fp8_fp8(af, bf8, acc[nf],
                                                             0, 0, 0);
      }
    }
    __syncthreads();
    cur ^= 1;
  }

  unsigned short* V1 = mh ? V1b : V1a;
  const int b = head >> 3, h = head & 7;
#pragma unroll
  for (int r = 0; r < 4; ++r) {
    int n = n0 + w * 16 + ls * 4 + r;
    size_t li = (size_t)head * 1024 + n;
    float lv = lsum_g[li] + lsum_g[32768 + li] + lsum_g[65536 + li] +
               lsum_g[98304 + li];
    float rinv = (lv > 0.f) ? 1.f / lv : 0.f;
#pragma unroll
    for (int nf = 0; nf < 4; ++nf)
      V1[((size_t)b * 1024 + n) * 512 + h * 64 + nf * 16 + lr] =
          f2bf(acc[nf][r] * rinv);
  }
}

// ---------------------------------------------------------------------------
// Fused LayerNorm (+ optional transpose): y = LN(V1a+V1b+Vf).
// Grid 1024, 4 rows/block, one wave per row. Vf bf16 (R15).
// mode 0: bf16 Vt (fallback). mode 1: fp8 Vt. mode 2: no Vt, f32 out.
// ---------------------------------------------------------------------------
__global__ __launch_bounds__(256) void k_ln_t(
    const unsigned short* __restrict__ V1a,
    const unsigned short* __restrict__ V1b,
    const unsigned short* __restrict__ Vf_in,
    const float* __restrict__ gamma, const float* __restrict__ beta,
    unsigned short* __restrict__ VfO, float* __restrict__ outF,
    void* __restrict__ Vt, int mode) {
  __shared__ unsigned short tile[4 * 520];
  const int blk = blockIdx.x;          // 0..1023
  const int b  = blk >> 8;
  const int n0 = (blk & 255) * 4;
  const int t = threadIdx.x;
  const int row = t >> 6;              // 0..3, one wave per row
  const int l = t & 63;
  const int c0 = l * 8;
  const size_t base = ((size_t)b * 1024 + n0 + row) * 512 + c0;

  float x[8];
  float s = 0.f, sq = 0.f;
  {
    ushort8 a0 = *(const ushort8*)(V1a + base);
    ushort8 a1 = *(const ushort8*)(V1b + base);
    ushort8 vv = *(const ushort8*)(Vf_in + base);
#pragma unroll
    for (int j = 0; j < 8; ++j) {
      float y = bf2f(a0[j]) + bf2f(a1[j]) + bf2f(vv[j]);
      x[j] = y;
      s += y;
      sq += y * y;
    }
  }
#pragma unroll
  for (int off = 1; off < 64; off <<= 1) {
    s  += __shfl_xor(s, off, 64);
    sq += __shfl_xor(sq, off, 64);
  }
  float mu   = s * (1.f / 512.f);
  float var  = sq * (1.f / 512.f) - mu * mu;
  float rstd = rsqrtf(var + 1e-5f);

  unsigned short* trow = tile + row * 520 + c0;
#pragma unroll
  for (int j = 0; j < 8; j += 4) {
    float4 g = *(const float4*)(gamma + c0 + j);
    float4 bb = *(const float4*)(beta + c0 + j);
    float4 y;
    y.x = (x[j + 0] - mu) * rstd * g.x + bb.x;
    y.y = (x[j + 1] - mu) * rstd * g.y + bb.y;
    y.z = (x[j + 2] - mu) * rstd * g.z + bb.z;
    y.w = (x[j + 3] - mu) * rstd * g.w + bb.w;
    if (mode == 2) {
      *(float4*)(outF + base + j) = y;
    } else {
      ushort4v yb;
      yb[0] = f2bf(y.x); yb[1] = f2bf(y.y);
      yb[2] = f2bf(y.z); yb[3] = f2bf(y.w);
      *(ushort4v*)(VfO + base + j) = yb;
      trow[j + 0] = yb[0]; trow[j + 1] = yb[1];
      trow[j + 2] = yb[2]; trow[j + 3] = yb[3];
    }
  }
  if (mode == 2) return;
  __syncthreads();

#pragma unroll
  for (int it = 0; it < 2; ++it) {
    int d = t + it * 256;              // 0..511 = h*64+dh
    int h = d >> 6, dh = d & 63;
    int sw = (dh & 7) << 4;
    if (mode == 0) {
      ushort4v o;
#pragma unroll
      for (int j = 0; j < 4; ++j) o[j] = tile[j * 520 + d];
      int byte0 = n0 * 2;
      char* dst = (char*)Vt + ((size_t)((b * 8 + h) * 64 + dh)) * 2048 +
                  (byte0 & ~127) + ((byte0 & 127) ^ sw);
      *(ushort4v*)dst = o;
    } else {
      uchar4v o;
#pragma unroll
      for (int j = 0; j < 4; ++j) o[j] = f2e4m3_fast(bf2f(tile[j * 520 + d]));
      char* dst = (char*)Vt + ((size_t)((b * 8 + h) * 64 + dh)) * 1024 +
                  (n0 & ~127) + ((n0 & 127) ^ sw);
      *(uchar4v*)dst = o;
    }
  }
}

// ---------------------------------------------------------------------------
// Fallback fused flash attention (ws too small only; bf16 Vt, bf16 V1 out)
// ---------------------------------------------------------------------------
__global__ __launch_bounds__(256) void k_attn(
    const unsigned short* __restrict__ Qb,
    const unsigned short* __restrict__ Kb,
    const unsigned short* __restrict__ Vt,
    unsigned short* __restrict__ V1) {
  __shared__ char lds[8192 + 8192 + 4 * 16 * 144];
  char* kbuf = lds;
  char* vbuf = lds + 8192;
  const int bh = blockIdx.y;
  const int q0 = blockIdx.x * 64;
  const int t = threadIdx.x;
  const int w = t >> 6, l = t & 63, lr = l & 15, ls = l >> 4;
  char* pbuf = lds + 16384 + w * (16 * 144);

  const float scale = 0.044194173824159216f;

  short8 qa[2];
  {
    const unsigned short* Qg =
        Qb + ((size_t)bh * 1024 + q0 + w * 16 + lr) * 64 + ls * 8;
    qa[0] = *(const short8*)(Qg);
    qa[1] = *(const short8*)(Qg + 32);
  }

  f32x4 O[4] = {};
  float mrow[4], lrow[4];
#pragma unroll
  for (int r = 0; r < 4; ++r) { mrow[r] = -INFINITY; lrow[r] = 0.f; }

  const unsigned short* Kg = Kb + (size_t)bh * 1024 * 64;
  const char* Vg = (const char*)(Vt + (size_t)bh * 64 * 1024);

  for (int kc = 0; kc < 16; ++kc) {
    {
      int row = t >> 3;
      int c8  = (t & 7) * 8;
#pragma unroll
      for (int it = 0; it < 2; ++it) {
        int rr = row + it * 32;
        int4 kv = *(const int4*)(Kg + (size_t)(kc * 64 + rr) * 64 + c8);
        *(int4*)(kbuf + swz(rr, c8 * 2)) = kv;
        int swv = (rr & 7) << 4;
        int4 vv = *(const int4*)(Vg + (size_t)rr * 2048 + kc * 128 +
                                 ((c8 * 2) ^ swv));
        *(int4*)(vbuf + swz(rr, c8 * 2)) = vv;
      }
    }
    __syncthreads();

    f32x4 s[4] = {};
#pragma unroll
    for (int kk = 0; kk < 2; ++kk) {
#pragma unroll
      for (int nt = 0; nt < 4; ++nt) {
        short8 bk = *(const short8*)(kbuf + swz(nt * 16 + lr, kk * 64 + ls * 16));
        s[nt] = mfma_bf16(qa[kk], bk, s[nt]);
      }
    }

    float p[4][4];
    float cmax[4];
#pragma unroll
    for (int r = 0; r < 4; ++r) cmax[r] = -INFINITY;
#pragma unroll
    for (int nt = 0; nt < 4; ++nt)
#pragma unroll
      for (int r = 0; r < 4; ++r) {
        float sv = s[nt][r];
        p[nt][r] = (sv == 0.f) ? -INFINITY : sv * scale;
        cmax[r] = fmaxf(cmax[r], p[nt][r]);
      }
#pragma unroll
    for (int r = 0; r < 4; ++r)
#pragma unroll
      for (int off = 1; off < 16; off <<= 1)
        cmax[r] = fmaxf(cmax[r], __shfl_xor(cmax[r], off, 64));

    float alpha[4];
#pragma unroll
    for (int r = 0; r < 4; ++r) {
      float mnew = fmaxf(mrow[r], cmax[r]);
      alpha[r] = (mnew == -INFINITY) ? 1.f : exp2f((mrow[r] - mnew) * LOG2E);
      mrow[r] = mnew;
    }
    float lsum[4] = {0.f, 0.f, 0.f, 0.f};
#pragma unroll
    for (int nt = 0; nt < 4; ++nt)
#pragma unroll
      for (int r = 0; r < 4; ++r) {
        float pv = (p[nt][r] == -INFINITY)
                       ? 0.f
                       : exp2f((p[nt][r] - mrow[r]) * LOG2E);
        p[nt][r] = pv;
        lsum[r] += pv;
      }
#pragma unroll
    for (int r = 0; r < 4; ++r) {
#pragma unroll
      for (int off = 1; off < 16; off <<= 1)
        lsum[r] += __shfl_xor(lsum[r], off, 64);
      lrow[r] = lrow[r] * alpha[r] + lsum[r];
    }
#pragma unroll
    for (int dt = 0; dt < 4; ++dt)
#pragma unroll
      for (int r = 0; r < 4; ++r) O[dt][r] *= alpha[r];

#pragma unroll
    for (int nt = 0; nt < 4; ++nt)
#pragma unroll
      for (int r = 0; r < 4; ++r)
        *(unsigned short*)(pbuf + (ls * 4 + r) * 144 + (nt * 16 + lr) * 2) =
            f2bf(p[nt][r]);

#pragma unroll
    for (int kk = 0; kk < 2; ++kk) {
      short8 pa = *(const short8*)(pbuf + lr * 144 + kk * 64 + ls * 16);
#pragma unroll
      for (int dt = 0; dt < 4; ++dt) {
        short8 bv = *(const short8*)(vbuf + swz(dt * 16 + lr, kk * 64 + ls * 16));
        O[dt] = mfma_bf16(pa, bv, O[dt]);
      }
    }
    __syncthreads();
  }

  float rinv[4];
#pragma unroll
  for (int r = 0; r < 4; ++r) rinv[r] = (lrow[r] > 0.f) ? 1.f / lrow[r] : 0.f;
  const int b = bh >> 3, h = bh & 7;
#pragma unroll
  for (int dt = 0; dt < 4; ++dt)
#pragma unroll
    for (int r = 0; r < 4; ++r) {
      int n = q0 + w * 16 + ls * 4 + r;
      int c = h * 64 + dt * 16 + lr;
      V1[((size_t)b * 1024 + n) * 512 + c] = f2bf(O[dt][r] * rinv[r]);
    }
}

// ---------------------------------------------------------------------------
extern "C" void kernel_launch(void* const* d_in, const int* in_sizes, int n_in,
                              void* d_out, int out_size, void* d_ws,
                              size_t ws_size, hipStream_t stream) {
  const float* x1    = (const float*)d_in[0];
  const float* x2    = (const float*)d_in[1];
  const float* Wq    = (const float*)d_in[2];
  const float* Wk    = (const float*)d_in[3];
  const float* Wv    = (const float*)d_in[4];
  const float* gamma = (const float*)d_in[5];
  const float* beta  = (const float*)d_in[6];
  float* out = (float*)d_out;
  char* ws = (char*)d_ws;

  const size_t MB = 1u << 20;
  unsigned short* xb  = (unsigned short*)(ws);                 // 8 MB (dead after proj)
  unsigned short* Wqb = (unsigned short*)(ws + 8 * MB);
  unsigned short* Wkb = (unsigned short*)(ws + 8 * MB + 512 * 1024);
  unsigned short* Wvb = (unsigned short*)(ws + 9 * MB);
  unsigned short* Qb  = (unsigned short*)(ws + 10 * MB);       // 4 MB
  unsigned short* Kb  = (unsigned short*)(ws + 14 * MB);       // 4 MB
  void*           Vt  = (void*)(ws + 18 * MB);                 // 4 MB bf16 / 2 MB fp8
  unsigned short* Vf  = (unsigned short*)(ws + 22 * MB);       // 4 MB (bf16)
  unsigned short* V1a = (unsigned short*)(ws + 30 * MB);       // 4 MB (bf16)
  float*          lsm = (float*)(ws + 38 * MB);                // 512 KB
  unsigned char*  Pm  = (unsigned char*)(ws + 39 * MB);        // 32 MB (fp8)
  unsigned short* V1b = (unsigned short*)(ws);                 // reuse xb region

  const bool bigws = ws_size >= (size_t)71 * MB;

  k_convert_all<<<2560, 256, 0, stream>>>(x1, x2, Wq, Wk, Wv, xb, Wqb, Wkb,
                                          Wvb);
  k_proj<<<768, 256, 0, stream>>>(xb, Wqb, Wkb, Wvb, Qb, Kb, Vf,
                                  (unsigned char*)Vt, bigws ? 1 : 0);

  if (bigws) {
    k_scores<<<2048, 256, 0, stream>>>(Qb, Kb, Pm, lsm);
    for (int layer = 0; layer < 3; ++layer) {
      k_pv<<<1024, 256, 0, stream>>>(Pm, (const unsigned char*)Vt, lsm, V1a,
                                     V1b);
      if (layer < 2)
        k_ln_t<<<1024, 256, 0, stream>>>(V1a, V1b, Vf, gamma, beta, Vf, out,
                                         Vt, 1);
      else
        k_ln_t<<<1024, 256, 0, stream>>>(V1a, V1b, Vf, gamma, beta, Vf, out,
                                         Vt, 2);
    }
  } else {
    hipMemsetAsync(V1b, 0, 4 * MB, stream);
    k_transpose_v<<<dim3(16, 32), 256, 0, stream>>>(Vf, Vt);
    for (int layer = 0; layer < 3; ++layer) {
      k_attn<<<dim3(16, 32), 256, 0, stream>>>(Qb, Kb,
                                               (const unsigned short*)Vt, V1a);
      if (layer < 2)
        k_ln_t<<<1024, 256, 0, stream>>>(V1a, V1b, Vf, gamma, beta, Vf, out,
                                         Vt, 0);
      else
        k_ln_t<<<1024, 256, 0, stream>>>(V1a, V1b, Vf, gamma, beta, Vf, out,
                                         Vt, 2);
    }
  }
}